// Round 13
// baseline (607.626 us; speedup 1.0000x reference)
//
#include <hip/hip_runtime.h>

// ---------------------------------------------------------------------------
// GeneralGNN: 4-layer GCN (skip='all') + MLP head.
// Round 13: fused_post -> 512 threads, 128-row tile, 8 waves (2Mx4N).
// 2x MFMA per barrier phase + 16 waves/CU (was ~5.6 measured). LDS 80KB:
// R0 32K (H1 then H3) | R1 32K (Am 16K then H2) | Bls 16K.
// Everything else unchanged from round 12.
// ---------------------------------------------------------------------------

typedef __bf16 bf16;
typedef __attribute__((ext_vector_type(8))) __bf16 bf16x8;
typedef __attribute__((ext_vector_type(4))) float f32x4;

#define BSHIFT 9                 // bucket = dst >> 9  (512 nodes/bucket)
#define PCHUNK 4096              // edges per partition block

// ---- Pass A: per-(bucket, block) counts; no global atomics ----
__global__ __launch_bounds__(256) void part_count(const int* __restrict__ ei,
                                                  int* __restrict__ bcountT,
                                                  int NBKT, int NBLK, int E) {
    __shared__ int cnt[256];
    const int t = threadIdx.x, blk = blockIdx.x;
    if (t < NBKT) cnt[t] = 0;
    __syncthreads();
    const int base = blk * PCHUNK;
#pragma unroll
    for (int i = 0; i < 16; ++i) {
        int e = base + i * 256 + t;
        if (e < E) atomicAdd(&cnt[ei[E + e] >> BSHIFT], 1);   // LDS atomic
    }
    __syncthreads();
    if (t < NBKT) bcountT[t * NBLK + blk] = cnt[t];
}

// ---- Pass B: per-bucket exclusive scan of its row (across blocks) ----
__global__ __launch_bounds__(256) void part_scanb(int* __restrict__ bcountT,
                                                  int* __restrict__ btot, int NBLK) {
    __shared__ int sums[256];
    const int b = blockIdx.x, t = threadIdx.x;
    int* row = &bcountT[(size_t)b * NBLK];
    const int chunk = (NBLK + 255) / 256;
    const int lo = t * chunk, hi = min(lo + chunk, NBLK);
    int s = 0;
    for (int i = lo; i < hi; ++i) s += row[i];
    sums[t] = s;
    __syncthreads();
#pragma unroll
    for (int off = 1; off < 256; off <<= 1) {
        int u = (t >= off) ? sums[t - off] : 0;
        __syncthreads();
        sums[t] += u;
        __syncthreads();
    }
    int run = sums[t] - s;
    for (int i = lo; i < hi; ++i) { int c = row[i]; row[i] = run; run += c; }
    if (t == 255) btot[b] = sums[255];
}

// ---- Pass B2: bucket bases (exclusive scan of btot); bbase[NBKT] = E ----
__global__ __launch_bounds__(256) void part_scant(const int* __restrict__ btot,
                                                  int* __restrict__ bbase, int NBKT, int E) {
    __shared__ int sums[256];
    const int t = threadIdx.x;
    int s = (t < NBKT) ? btot[t] : 0;
    sums[t] = s;
    __syncthreads();
#pragma unroll
    for (int off = 1; off < 256; off <<= 1) {
        int u = (t >= off) ? sums[t - off] : 0;
        __syncthreads();
        sums[t] += u;
        __syncthreads();
    }
    if (t < NBKT) bbase[t] = sums[t] - s;
    if (t == 0) bbase[NBKT] = E;
}

// ---- Pass C: scatter edges to bucket-sorted order ----
__global__ __launch_bounds__(256) void part_scatter(const int* __restrict__ ei,
                                                    const int* __restrict__ bcountT,
                                                    const int* __restrict__ bbase,
                                                    int2* __restrict__ sorted,
                                                    int NBKT, int NBLK, int E) {
    __shared__ int cur[256];
    const int t = threadIdx.x, blk = blockIdx.x;
    if (t < NBKT) cur[t] = bbase[t] + bcountT[(size_t)t * NBLK + blk];
    __syncthreads();
    const int base = blk * PCHUNK;
#pragma unroll
    for (int i = 0; i < 16; ++i) {
        int e = base + i * 256 + t;
        if (e < E) {
            int src = ei[e], dst = ei[E + e];
            int pos = atomicAdd(&cur[dst >> BSHIFT], 1);      // LDS atomic
            sorted[pos] = make_int2(src, dst);
        }
    }
}

// ---- Pass D: per-bucket CSR rows + rp + dinv (all traffic L2-local) ----
__global__ __launch_bounds__(512) void bucket_csr(const int2* __restrict__ sorted,
                                                  const int* __restrict__ bbase,
                                                  int* __restrict__ rp,
                                                  float* __restrict__ dinv,
                                                  int* __restrict__ csr,
                                                  int n, int E) {
    __shared__ int cnt[512];
    __shared__ int cur[512];
    const int b = blockIdx.x, t = threadIdx.x;
    const int nb0 = b << BSHIFT;
    const int lo = bbase[b], hi = bbase[b + 1];
    cnt[t] = 0;
    __syncthreads();
    for (int k = lo + t; k < hi; k += 512)
        atomicAdd(&cnt[sorted[k].y - nb0], 1);                // LDS atomic
    __syncthreads();
    const int own = cnt[t];
    cur[t] = own;
    __syncthreads();
#pragma unroll
    for (int off = 1; off < 512; off <<= 1) {
        int u = (t >= off) ? cur[t - off] : 0;
        __syncthreads();
        cur[t] += u;
        __syncthreads();
    }
    const int excl = cur[t] - own;
    const int node = nb0 + t;
    if (node < n) {
        rp[node] = lo + excl;
        dinv[node] = rsqrtf((float)(own + 1));
    }
    if (b == 0 && t == 0) rp[n] = E;
    __syncthreads();
    cur[t] = excl;
    __syncthreads();
    for (int k = lo + t; k < hi; k += 512) {
        int2 e = sorted[k];
        int pos = atomicAdd(&cur[e.y - nb0], 1);              // LDS atomic
        csr[lo + pos] = e.x;
    }
}

// ---------------- weight transposes (one launch) ----------------
struct TAll {
    const float* src[9];
    int cum[10];
    int N[9];
    int K[9];
};
__global__ __launch_bounds__(256) void transpose_all(TAll d, bf16* __restrict__ wt, int total) {
    int idx = blockIdx.x * 256 + threadIdx.x;
    if (idx >= total) return;
    int seg = 0;
#pragma unroll
    for (int s = 1; s < 9; ++s) if (idx >= d.cum[s]) seg = s;
    int local = idx - d.cum[seg];
    int N = d.N[seg], K = d.K[seg];
    int k = local / N;
    int nn = local - k * N;
    wt[d.cum[seg] + (size_t)nn * K + k] = (bf16)d.src[seg][local];
}

// ---------------- LDS-layout helpers ----------------
__device__ __forceinline__ void stash_lds(char* H, int ktStride, int r, int c, float v) {
    int kt = c >> 6, w = c & 63;
    int byte = kt * ktStride + r * 128 + (((w >> 3) ^ (r & 7)) * 8 + (w & 7)) * 2;
    *(bf16*)(H + byte) = (bf16)v;
}
__device__ __forceinline__ bf16x8 afrag_lds(const char* H, int ktStride, int kt, int r, int ks, int lane) {
    int ch = (ks * 4 + (lane >> 4)) ^ (r & 7);
    return *(const bf16x8*)(H + kt * ktStride + r * 128 + ch * 16);
}

// ---------------- bf16 MFMA GEMM (conv1..3) ----------------
__global__ __launch_bounds__(256) void gemm_bf16(
    const bf16* __restrict__ A1, int lda1, int K1,
    const bf16* __restrict__ A2, int lda2,
    const bf16* __restrict__ WT,
    const float* __restrict__ bias,
    const float* __restrict__ rowscale,
    void* __restrict__ Cout, int ldc, int M, int Ktot,
    int act, int outf32)
{
    __shared__ bf16 Als[128 * 64];
    __shared__ bf16 Bls[128 * 64];

    const int t = threadIdx.x;
    const int lane = t & 63;
    const int wid = t >> 6;
    const int wm = wid >> 1, wn = wid & 1;
    const int row0 = blockIdx.x * 128;
    const int col0 = blockIdx.y * 128;
    const int nt = Ktot >> 6;

    f32x4 acc[4][4];
#pragma unroll
    for (int mf = 0; mf < 4; ++mf)
#pragma unroll
        for (int nf = 0; nf < 4; ++nf) {
            f32x4 z = {0.f, 0.f, 0.f, 0.f};
            acc[mf][nf] = z;
        }

    int srow[4], scs[4];
#pragma unroll
    for (int i = 0; i < 4; ++i) {
        int ch = wid * 64 + i * 256 + lane;
        int row = ch >> 3, c = ch & 7;
        srow[i] = row;
        scs[i] = (c ^ (row & 7)) * 8;
    }

    for (int kt = 0; kt < nt; ++kt) {
        const int k0 = kt * 64;
        const bf16* Ap; int lda_, kk;
        if (k0 < K1) { Ap = A1; lda_ = lda1; kk = k0; }
        else         { Ap = A2; lda_ = lda2; kk = k0 - K1; }

        __syncthreads();
#pragma unroll
        for (int i = 0; i < 4; ++i) {
            int grow = row0 + srow[i]; if (grow >= M) grow = M - 1;
            const bf16* ga = &Ap[(size_t)grow * lda_ + kk + scs[i]];
            const bf16* gb = &WT[(size_t)(col0 + srow[i]) * Ktot + k0 + scs[i]];
            bf16* la = &Als[(size_t)(wid * 64 + i * 256) * 8];
            bf16* lb = &Bls[(size_t)(wid * 64 + i * 256) * 8];
            __builtin_amdgcn_global_load_lds(
                (const __attribute__((address_space(1))) void*)ga,
                (__attribute__((address_space(3))) void*)la, 16, 0, 0);
            __builtin_amdgcn_global_load_lds(
                (const __attribute__((address_space(1))) void*)gb,
                (__attribute__((address_space(3))) void*)lb, 16, 0, 0);
        }
        asm volatile("s_waitcnt vmcnt(0)" ::: "memory");
        __syncthreads();

#pragma unroll
        for (int ks = 0; ks < 2; ++ks) {
            bf16x8 af[4], bfr[4];
#pragma unroll
            for (int mf = 0; mf < 4; ++mf) {
                int r = wm * 64 + mf * 16 + (lane & 15);
                int ch = (ks * 4 + (lane >> 4)) ^ (r & 7);
                af[mf] = *(const bf16x8*)((const char*)Als + r * 128 + ch * 16);
            }
#pragma unroll
            for (int nf = 0; nf < 4; ++nf) {
                int r = wn * 64 + nf * 16 + (lane & 15);
                int ch = (ks * 4 + (lane >> 4)) ^ (r & 7);
                bfr[nf] = *(const bf16x8*)((const char*)Bls + r * 128 + ch * 16);
            }
#pragma unroll
            for (int mf = 0; mf < 4; ++mf)
#pragma unroll
                for (int nf = 0; nf < 4; ++nf)
                    acc[mf][nf] = __builtin_amdgcn_mfma_f32_16x16x32_bf16(
                        af[mf], bfr[nf], acc[mf][nf], 0, 0, 0);
        }
    }

#pragma unroll
    for (int mf = 0; mf < 4; ++mf) {
        int rbase = row0 + wm * 64 + mf * 16 + (lane >> 4) * 4;
#pragma unroll
        for (int nf = 0; nf < 4; ++nf) {
            int gcol = col0 + wn * 64 + nf * 16 + (lane & 15);
            float bv = bias ? bias[gcol] : 0.f;
#pragma unroll
            for (int i = 0; i < 4; ++i) {
                int grow = rbase + i;
                if (grow >= M) continue;
                float v = acc[mf][nf][i];
                if (rowscale) v *= rowscale[grow];
                v += bv;
                if (act == 1) v = fmaxf(v, 0.f);
                else if (act == 2) v = v > 0.f ? v : 0.1f * v;
                if (outf32) ((float*)Cout)[(size_t)grow * ldc + gcol] = v;
                else        ((bf16*)Cout)[(size_t)grow * ldc + gcol] = (bf16)v;
            }
        }
    }
}

// ---------------- fused_pre: emb = x@W0+b0 ; g = dinv*(emb@Wc0) ----------------
__global__ __launch_bounds__(256) void fused_pre(
    const float* __restrict__ x,
    const bf16* __restrict__ preWT,
    const float* __restrict__ pre_b,
    const bf16* __restrict__ c0WT,
    const float* __restrict__ dinv,
    bf16* __restrict__ emb, int lde,
    bf16* __restrict__ g, int M)
{
    __shared__ char lds[49152];
    bf16* Hbuf = (bf16*)lds;
    bf16* Bls  = (bf16*)(lds + 32768);
    bf16* Als  = Hbuf;

    const int t = threadIdx.x;
    const int lane = t & 63;
    const int wid = t >> 6;
    const int wm = wid >> 1, wn = wid & 1;
    const int row0 = blockIdx.x * 128;

    int srow[4], scs[4];
#pragma unroll
    for (int i = 0; i < 4; ++i) {
        int ch = wid * 64 + i * 256 + lane;
        int row = ch >> 3, c = ch & 7;
        srow[i] = row;
        scs[i] = (c ^ (row & 7)) * 8;
    }

    f32x4 acc[4][4];
#pragma unroll
    for (int mf = 0; mf < 4; ++mf)
#pragma unroll
        for (int nf = 0; nf < 4; ++nf) { f32x4 z = {0,0,0,0}; acc[mf][nf] = z; }

    for (int kt = 0; kt < 2; ++kt) {
        __syncthreads();
#pragma unroll
        for (int i = 0; i < 4; ++i) {
            int grow = row0 + srow[i]; if (grow >= M) grow = M - 1;
            const float* gx = &x[(size_t)grow * 128 + kt * 64 + scs[i]];
            float4 f0 = *(const float4*)gx;
            float4 f1 = *(const float4*)(gx + 4);
            bf16x8 av = {(bf16)f0.x, (bf16)f0.y, (bf16)f0.z, (bf16)f0.w,
                         (bf16)f1.x, (bf16)f1.y, (bf16)f1.z, (bf16)f1.w};
            *(bf16x8*)((char*)Als + (size_t)(wid * 64 + i * 256 + lane) * 16) = av;
            const bf16* gb = &preWT[(size_t)srow[i] * 128 + kt * 64 + scs[i]];
            bf16* lb = &Bls[(size_t)(wid * 64 + i * 256) * 8];
            __builtin_amdgcn_global_load_lds(
                (const __attribute__((address_space(1))) void*)gb,
                (__attribute__((address_space(3))) void*)lb, 16, 0, 0);
        }
        asm volatile("s_waitcnt vmcnt(0)" ::: "memory");
        __syncthreads();
#pragma unroll
        for (int ks = 0; ks < 2; ++ks) {
            bf16x8 af[4], bfr[4];
#pragma unroll
            for (int mf = 0; mf < 4; ++mf) {
                int r = wm * 64 + mf * 16 + (lane & 15);
                int ch = (ks * 4 + (lane >> 4)) ^ (r & 7);
                af[mf] = *(const bf16x8*)((const char*)Als + r * 128 + ch * 16);
            }
#pragma unroll
            for (int nf = 0; nf < 4; ++nf) {
                int r = wn * 64 + nf * 16 + (lane & 15);
                int ch = (ks * 4 + (lane >> 4)) ^ (r & 7);
                bfr[nf] = *(const bf16x8*)((const char*)Bls + r * 128 + ch * 16);
            }
#pragma unroll
            for (int mf = 0; mf < 4; ++mf)
#pragma unroll
                for (int nf = 0; nf < 4; ++nf)
                    acc[mf][nf] = __builtin_amdgcn_mfma_f32_16x16x32_bf16(
                        af[mf], bfr[nf], acc[mf][nf], 0, 0, 0);
        }
    }
    __syncthreads();

#pragma unroll
    for (int mf = 0; mf < 4; ++mf) {
        int rl = wm * 64 + mf * 16 + (lane >> 4) * 4;
#pragma unroll
        for (int nf = 0; nf < 4; ++nf) {
            int c = wn * 64 + nf * 16 + (lane & 15);
            float bv = pre_b[c];
#pragma unroll
            for (int i = 0; i < 4; ++i) {
                int r = rl + i;
                float v = acc[mf][nf][i] + bv;
                stash_lds((char*)Hbuf, 16384, r, c, v);
                int grow = row0 + r;
                if (grow < M) emb[(size_t)grow * lde + c] = (bf16)v;
            }
        }
    }

#pragma unroll
    for (int mf = 0; mf < 4; ++mf)
#pragma unroll
        for (int nf = 0; nf < 4; ++nf) { f32x4 z = {0,0,0,0}; acc[mf][nf] = z; }

    for (int kt = 0; kt < 2; ++kt) {
        __syncthreads();
#pragma unroll
        for (int i = 0; i < 4; ++i) {
            const bf16* gb = &c0WT[(size_t)srow[i] * 128 + kt * 64 + scs[i]];
            bf16* lb = &Bls[(size_t)(wid * 64 + i * 256) * 8];
            __builtin_amdgcn_global_load_lds(
                (const __attribute__((address_space(1))) void*)gb,
                (__attribute__((address_space(3))) void*)lb, 16, 0, 0);
        }
        asm volatile("s_waitcnt vmcnt(0)" ::: "memory");
        __syncthreads();
#pragma unroll
        for (int ks = 0; ks < 2; ++ks) {
            bf16x8 af[4], bfr[4];
#pragma unroll
            for (int mf = 0; mf < 4; ++mf) {
                int r = wm * 64 + mf * 16 + (lane & 15);
                af[mf] = afrag_lds((const char*)Hbuf, 16384, kt, r, ks, lane);
            }
#pragma unroll
            for (int nf = 0; nf < 4; ++nf) {
                int r = wn * 64 + nf * 16 + (lane & 15);
                int ch = (ks * 4 + (lane >> 4)) ^ (r & 7);
                bfr[nf] = *(const bf16x8*)((const char*)Bls + r * 128 + ch * 16);
            }
#pragma unroll
            for (int mf = 0; mf < 4; ++mf)
#pragma unroll
                for (int nf = 0; nf < 4; ++nf)
                    acc[mf][nf] = __builtin_amdgcn_mfma_f32_16x16x32_bf16(
                        af[mf], bfr[nf], acc[mf][nf], 0, 0, 0);
        }
    }

#pragma unroll
    for (int mf = 0; mf < 4; ++mf) {
        int rbase = row0 + wm * 64 + mf * 16 + (lane >> 4) * 4;
#pragma unroll
        for (int nf = 0; nf < 4; ++nf) {
            int c = wn * 64 + nf * 16 + (lane & 15);
#pragma unroll
            for (int i = 0; i < 4; ++i) {
                int grow = rbase + i;
                if (grow >= M) continue;
                g[(size_t)grow * 128 + c] = (bf16)(acc[mf][nf][i] * dinv[grow]);
            }
        }
    }
}

// ---------------- fused_post: [emb|h4] -> h1 -> h2 -> h3 -> out ----------------
// 512 threads, 128-row tile, 8 waves (2M x 4N, per-wave 64x32, acc[4][2]).
// LDS 80KB: R0@0 32K (H1, then H3) | R1@32K 32K (Am 16K, then H2) | Bls@64K 16K.
__global__ __launch_bounds__(512) void fused_post(
    const bf16* __restrict__ emb, int lde,
    const bf16* __restrict__ h4,     // n x 128
    const bf16* __restrict__ W1T,    // [128][640]
    const float* __restrict__ b1,
    const bf16* __restrict__ W2T,    // [128][128]
    const float* __restrict__ b2,
    const bf16* __restrict__ W3T,    // [256][128]
    const float* __restrict__ b3,
    const bf16* __restrict__ W4T,    // [128][256]
    const float* __restrict__ b4,
    float* __restrict__ out, int M)
{
    __shared__ char lds[81920];
    bf16* H1  = (bf16*)lds;              // 32K: 2kt x 128r x 128B
    bf16* H3  = (bf16*)lds;              // overlays H1 (dead after stage 1)
    bf16* Am  = (bf16*)(lds + 32768);    // 16K stage-0/1 A region (stage1 reads H1)
    bf16* H2  = (bf16*)(lds + 32768);    // 32K after stage-1 epilogue
    bf16* Bls = (bf16*)(lds + 65536);    // 16K

    const int t = threadIdx.x;           // 0..511
    const int lane = t & 63;
    const int wid = t >> 6;              // 0..7
    const int wm = wid >> 2;             // 0..1 (64 rows each)
    const int wn = wid & 3;              // 0..3 (32 cols each)
    const int row0 = blockIdx.x * 128;

    // staging: 1024 chunks per 128x64 tile, 2 per thread
    int srow[2], scs[2];
#pragma unroll
    for (int i = 0; i < 2; ++i) {
        int ch = wid * 64 + i * 512 + lane;
        int row = ch >> 3, c = ch & 7;
        srow[i] = row;
        scs[i] = (c ^ (row & 7)) * 8;
    }

    f32x4 acc[4][2], acc3[4][2];
#pragma unroll
    for (int mf = 0; mf < 4; ++mf)
#pragma unroll
        for (int nf = 0; nf < 2; ++nf) {
            f32x4 z = {0,0,0,0};
            acc[mf][nf] = z;
            acc3[mf][nf] = z;
        }

    // ---- stage 0: h1 = LeakyReLU([emb|h4] @ W1T^T + b1), K=640 ----
    for (int kt = 0; kt < 10; ++kt) {
        const int k0 = kt * 64;
        __syncthreads();
#pragma unroll
        for (int i = 0; i < 2; ++i) {
            int grow = row0 + srow[i]; if (grow >= M) grow = M - 1;
            const bf16* ga = (k0 < 512)
                ? &emb[(size_t)grow * lde + k0 + scs[i]]
                : &h4[(size_t)grow * 128 + (k0 - 512) + scs[i]];
            bf16* la = &Am[(size_t)(wid * 64 + i * 512) * 8];
            __builtin_amdgcn_global_load_lds(
                (const __attribute__((address_space(1))) void*)ga,
                (__attribute__((address_space(3))) void*)la, 16, 0, 0);
            const bf16* gb = &W1T[(size_t)srow[i] * 640 + k0 + scs[i]];
            bf16* lb = &Bls[(size_t)(wid * 64 + i * 512) * 8];
            __builtin_amdgcn_global_load_lds(
                (const __attribute__((address_space(1))) void*)gb,
                (__attribute__((address_space(3))) void*)lb, 16, 0, 0);
        }
        asm volatile("s_waitcnt vmcnt(0)" ::: "memory");
        __syncthreads();
#pragma unroll
        for (int ks = 0; ks < 2; ++ks) {
            bf16x8 af[4], bfr[2];
#pragma unroll
            for (int mf = 0; mf < 4; ++mf) {
                int r = wm * 64 + mf * 16 + (lane & 15);
                int ch = (ks * 4 + (lane >> 4)) ^ (r & 7);
                af[mf] = *(const bf16x8*)((const char*)Am + r * 128 + ch * 16);
            }
#pragma unroll
            for (int nf = 0; nf < 2; ++nf) {
                int r = wn * 32 + nf * 16 + (lane & 15);
                int ch = (ks * 4 + (lane >> 4)) ^ (r & 7);
                bfr[nf] = *(const bf16x8*)((const char*)Bls + r * 128 + ch * 16);
            }
#pragma unroll
            for (int mf = 0; mf < 4; ++mf)
#pragma unroll
                for (int nf = 0; nf < 2; ++nf)
                    acc[mf][nf] = __builtin_amdgcn_mfma_f32_16x16x32_bf16(
                        af[mf], bfr[nf], acc[mf][nf], 0, 0, 0);
        }
    }
    __syncthreads();
    // epilogue 0 -> H1 (LeakyReLU 0.1); ktStride = 128r*128B = 16384
#pragma unroll
    for (int mf = 0; mf < 4; ++mf) {
        int rl = wm * 64 + mf * 16 + (lane >> 4) * 4;
#pragma unroll
        for (int nf = 0; nf < 2; ++nf) {
            int c = wn * 32 + nf * 16 + (lane & 15);
            float bv = b1[c];
#pragma unroll
            for (int i = 0; i < 4; ++i) {
                float v = acc[mf][nf][i] + bv;
                v = v > 0.f ? v : 0.1f * v;
                stash_lds((char*)H1, 16384, rl + i, c, v);
            }
        }
    }

    // ---- stage 1: h2 = relu(h1 @ W2T^T + b2), K=128 ----
#pragma unroll
    for (int mf = 0; mf < 4; ++mf)
#pragma unroll
        for (int nf = 0; nf < 2; ++nf) { f32x4 z = {0,0,0,0}; acc[mf][nf] = z; }
    for (int kt = 0; kt < 2; ++kt) {
        __syncthreads();
#pragma unroll
        for (int i = 0; i < 2; ++i) {
            const bf16* gb = &W2T[(size_t)srow[i] * 128 + kt * 64 + scs[i]];
            bf16* lb = &Bls[(size_t)(wid * 64 + i * 512) * 8];
            __builtin_amdgcn_global_load_lds(
                (const __attribute__((address_space(1))) void*)gb,
                (__attribute__((address_space(3))) void*)lb, 16, 0, 0);
        }
        asm volatile("s_waitcnt vmcnt(0)" ::: "memory");
        __syncthreads();
#pragma unroll
        for (int ks = 0; ks < 2; ++ks) {
            bf16x8 af[4], bfr[2];
#pragma unroll
            for (int mf = 0; mf < 4; ++mf) {
                int r = wm * 64 + mf * 16 + (lane & 15);
                af[mf] = afrag_lds((const char*)H1, 16384, kt, r, ks, lane);
            }
#pragma unroll
            for (int nf = 0; nf < 2; ++nf) {
                int r = wn * 32 + nf * 16 + (lane & 15);
                int ch = (ks * 4 + (lane >> 4)) ^ (r & 7);
                bfr[nf] = *(const bf16x8*)((const char*)Bls + r * 128 + ch * 16);
            }
#pragma unroll
            for (int mf = 0; mf < 4; ++mf)
#pragma unroll
                for (int nf = 0; nf < 2; ++nf)
                    acc[mf][nf] = __builtin_amdgcn_mfma_f32_16x16x32_bf16(
                        af[mf], bfr[nf], acc[mf][nf], 0, 0, 0);
        }
    }
    __syncthreads();   // all H1 reads + Am-region use complete
    // epilogue 1 -> H2 (overlays Am region)
#pragma unroll
    for (int mf = 0; mf < 4; ++mf) {
        int rl = wm * 64 + mf * 16 + (lane >> 4) * 4;
#pragma unroll
        for (int nf = 0; nf < 2; ++nf) {
            int c = wn * 32 + nf * 16 + (lane & 15);
            float bv = b2[c];
#pragma unroll
            for (int i = 0; i < 4; ++i)
                stash_lds((char*)H2, 16384, rl + i, c, fmaxf(acc[mf][nf][i] + bv, 0.f));
        }
    }

    // ---- halves: h3half = relu(h2 @ W3T^T + b3) ; out += h3half @ W4T^T ----
    for (int hh = 0; hh < 2; ++hh) {
#pragma unroll
        for (int mf = 0; mf < 4; ++mf)
#pragma unroll
            for (int nf = 0; nf < 2; ++nf) { f32x4 z = {0,0,0,0}; acc[mf][nf] = z; }
        // stage 2: acc = H2 @ W3T(half hh)
        for (int kt = 0; kt < 2; ++kt) {
            __syncthreads();
#pragma unroll
            for (int i = 0; i < 2; ++i) {
                const bf16* gb = &W3T[(size_t)(hh * 128 + srow[i]) * 128 + kt * 64 + scs[i]];
                bf16* lb = &Bls[(size_t)(wid * 64 + i * 512) * 8];
                __builtin_amdgcn_global_load_lds(
                    (const __attribute__((address_space(1))) void*)gb,
                    (__attribute__((address_space(3))) void*)lb, 16, 0, 0);
            }
            asm volatile("s_waitcnt vmcnt(0)" ::: "memory");
            __syncthreads();
#pragma unroll
            for (int ks = 0; ks < 2; ++ks) {
                bf16x8 af[4], bfr[2];
#pragma unroll
                for (int mf = 0; mf < 4; ++mf) {
                    int r = wm * 64 + mf * 16 + (lane & 15);
                    af[mf] = afrag_lds((const char*)H2, 16384, kt, r, ks, lane);
                }
#pragma unroll
                for (int nf = 0; nf < 2; ++nf) {
                    int r = wn * 32 + nf * 16 + (lane & 15);
                    int ch = (ks * 4 + (lane >> 4)) ^ (r & 7);
                    bfr[nf] = *(const bf16x8*)((const char*)Bls + r * 128 + ch * 16);
                }
#pragma unroll
                for (int mf = 0; mf < 4; ++mf)
#pragma unroll
                    for (int nf = 0; nf < 2; ++nf)
                        acc[mf][nf] = __builtin_amdgcn_mfma_f32_16x16x32_bf16(
                            af[mf], bfr[nf], acc[mf][nf], 0, 0, 0);
            }
        }
        __syncthreads();   // prev-H3 reads (hh-1 stage 3) + H1 dead
        // epilogue 2 -> H3
#pragma unroll
        for (int mf = 0; mf < 4; ++mf) {
            int rl = wm * 64 + mf * 16 + (lane >> 4) * 4;
#pragma unroll
            for (int nf = 0; nf < 2; ++nf) {
                int c = wn * 32 + nf * 16 + (lane & 15);
                float bv = b3[hh * 128 + c];
#pragma unroll
                for (int i = 0; i < 4; ++i)
                    stash_lds((char*)H3, 16384, rl + i, c, fmaxf(acc[mf][nf][i] + bv, 0.f));
            }
        }
        // stage 3: acc3 += H3 @ W4T (k range hh*128 .. +127)
        for (int kt = 0; kt < 2; ++kt) {
            __syncthreads();
#pragma unroll
            for (int i = 0; i < 2; ++i) {
                const bf16* gb = &W4T[(size_t)srow[i] * 256 + hh * 128 + kt * 64 + scs[i]];
                bf16* lb = &Bls[(size_t)(wid * 64 + i * 512) * 8];
                __builtin_amdgcn_global_load_lds(
                    (const __attribute__((address_space(1))) void*)gb,
                    (__attribute__((address_space(3))) void*)lb, 16, 0, 0);
            }
            asm volatile("s_waitcnt vmcnt(0)" ::: "memory");
            __syncthreads();
#pragma unroll
            for (int ks = 0; ks < 2; ++ks) {
                bf16x8 af[4], bfr[2];
#pragma unroll
                for (int mf = 0; mf < 4; ++mf) {
                    int r = wm * 64 + mf * 16 + (lane & 15);
                    af[mf] = afrag_lds((const char*)H3, 16384, kt, r, ks, lane);
                }
#pragma unroll
                for (int nf = 0; nf < 2; ++nf) {
                    int r = wn * 32 + nf * 16 + (lane & 15);
                    int ch = (ks * 4 + (lane >> 4)) ^ (r & 7);
                    bfr[nf] = *(const bf16x8*)((const char*)Bls + r * 128 + ch * 16);
                }
#pragma unroll
                for (int mf = 0; mf < 4; ++mf)
#pragma unroll
                    for (int nf = 0; nf < 2; ++nf)
                        acc3[mf][nf] = __builtin_amdgcn_mfma_f32_16x16x32_bf16(
                            af[mf], bfr[nf], acc3[mf][nf], 0, 0, 0);
            }
        }
    }

    // final epilogue: out = acc3 + b4 (f32)
#pragma unroll
    for (int mf = 0; mf < 4; ++mf) {
        int rbase = row0 + wm * 64 + mf * 16 + (lane >> 4) * 4;
#pragma unroll
        for (int nf = 0; nf < 2; ++nf) {
            int c = wn * 32 + nf * 16 + (lane & 15);
            float bv = b4[c];
#pragma unroll
            for (int i = 0; i < 4; ++i) {
                int grow = rbase + i;
                if (grow < M) out[(size_t)grow * 128 + c] = acc3[mf][nf][i] + bv;
            }
        }
    }
}

// ---------------- fused gather ----------------
__global__ __launch_bounds__(256) void gcn_gather(
    const int* __restrict__ rp, const int* __restrict__ csr,
    const bf16* __restrict__ g, const float* __restrict__ dinv,
    const float* __restrict__ b,
    bf16* __restrict__ out, int ldo, int n)
{
    const int node = (int)(((long long)blockIdx.x * 256 + threadIdx.x) >> 6);
    if (node >= n) return;
    const int lane = threadIdx.x & 63;
    const int grp = lane >> 4;
    const int cc = lane & 15;
    const int start = rp[node];
    const int end = rp[node + 1];

    float acc[8];
#pragma unroll
    for (int j = 0; j < 8; ++j) acc[j] = 0.f;

    int j = start + grp;
    for (; j + 12 < end; j += 16) {
        int s0 = csr[j];
        int s1 = csr[j + 4];
        int s2 = csr[j + 8];
        int s3 = csr[j + 12];
        bf16x8 v0 = *(const bf16x8*)&g[(size_t)s0 * 128 + cc * 8];
        bf16x8 v1 = *(const bf16x8*)&g[(size_t)s1 * 128 + cc * 8];
        bf16x8 v2 = *(const bf16x8*)&g[(size_t)s2 * 128 + cc * 8];
        bf16x8 v3 = *(const bf16x8*)&g[(size_t)s3 * 128 + cc * 8];
#pragma unroll
        for (int jj = 0; jj < 8; ++jj)
            acc[jj] += ((float)v0[jj] + (float)v1[jj]) + ((float)v2[jj] + (float)v3[jj]);
    }
    for (; j < end; j += 4) {
        int s0 = csr[j];
        bf16x8 v0 = *(const bf16x8*)&g[(size_t)s0 * 128 + cc * 8];
#pragma unroll
        for (int jj = 0; jj < 8; ++jj) acc[jj] += (float)v0[jj];
    }
#pragma unroll
    for (int jj = 0; jj < 8; ++jj) {
        acc[jj] += __shfl_xor(acc[jj], 16, 64);
        acc[jj] += __shfl_xor(acc[jj], 32, 64);
    }
    if (grp == 0) {
        bf16x8 sv = *(const bf16x8*)&g[(size_t)node * 128 + cc * 8];
        float s = dinv[node];
        bf16x8 o;
#pragma unroll
        for (int jj = 0; jj < 8; ++jj) {
            float v = fmaf(s, acc[jj] + (float)sv[jj], b[cc * 8 + jj]);
            o[jj] = (bf16)fmaxf(v, 0.f);
        }
        *(bf16x8*)&out[(size_t)node * ldo + cc * 8] = o;
    }
}

// ---------------- launcher ----------------
extern "C" void kernel_launch(void* const* d_in, const int* in_sizes, int n_in,
                              void* d_out, int out_size, void* d_ws, size_t ws_size,
                              hipStream_t stream) {
    const float* x      = (const float*)d_in[0];
    const int*   ei     = (const int*)d_in[1];
    const float* pre_w  = (const float*)d_in[2];
    const float* pre_b  = (const float*)d_in[3];
    const float* conv_w[4] = {(const float*)d_in[4], (const float*)d_in[6],
                              (const float*)d_in[8], (const float*)d_in[10]};
    const float* conv_b[4] = {(const float*)d_in[5], (const float*)d_in[7],
                              (const float*)d_in[9], (const float*)d_in[11]};
    const float* post_w1 = (const float*)d_in[12];
    const float* post_b1 = (const float*)d_in[13];
    const float* post_w2 = (const float*)d_in[14];
    const float* post_b2 = (const float*)d_in[15];
    const float* post_w3 = (const float*)d_in[16];
    const float* post_b3 = (const float*)d_in[17];
    const float* post_w4 = (const float*)d_in[18];
    const float* post_b4 = (const float*)d_in[19];

    const int n = in_sizes[0] / 128;        // 100000
    const int E = in_sizes[1] / 2;          // 1600000
    const int NBKT = (n + 511) >> BSHIFT;   // 196 buckets
    const int NBLK = (E + PCHUNK - 1) / PCHUNK;  // 391 partition blocks

    // ws layout (bytes)
    size_t off = 0;
    bf16* emb  = (bf16*)((char*)d_ws + off); off += (size_t)n * 512 * 2;
    bf16* g    = (bf16*)((char*)d_ws + off); off += (size_t)n * 128 * 2;
    bf16* h4   = (bf16*)((char*)d_ws + off); off += (size_t)n * 128 * 2;
    float* dinv = (float*)((char*)d_ws + off); off += (size_t)n * 4;
    int*   rp   = (int*)((char*)d_ws + off); off += (size_t)(n + 4) * 4;
    int*   csr  = (int*)((char*)d_ws + off); off += (size_t)E * 4;
    int2*  sorted = (int2*)((char*)d_ws + off); off += (size_t)E * 8;
    bf16*  wt   = (bf16*)((char*)d_ws + off); off += (size_t)344064 * 2;
    int*   bcountT = (int*)((char*)d_ws + off); off += (size_t)NBKT * NBLK * 4;
    int*   btot    = (int*)((char*)d_ws + off); off += (size_t)NBKT * 4;
    int*   bbase   = (int*)((char*)d_ws + off); off += (size_t)(NBKT + 1) * 4;
    if (ws_size < off) return;  // diagnostic early-out

    // weight-pool offsets (elements)
    bf16* pre_wt  = wt;            // [128][128]
    bf16* c_wt0   = wt + 16384;
    bf16* c_wt1   = wt + 32768;
    bf16* c_wt2   = wt + 65536;
    bf16* c_wt3   = wt + 114688;
    bf16* p1_wt   = wt + 180224;   // [128][640]
    bf16* p2_wt   = wt + 262144;
    bf16* p3_wt   = wt + 278528;   // [256][128]
    bf16* p4_wt   = wt + 311296;   // [128][256]
    bf16* c_wt[4] = {c_wt0, c_wt1, c_wt2, c_wt3};

    // ---- CSR build: bucket partition (no global atomics) ----
    part_count<<<NBLK, 256, 0, stream>>>(ei, bcountT, NBKT, NBLK, E);
    part_scanb<<<NBKT, 256, 0, stream>>>(bcountT, btot, NBLK);
    part_scant<<<1, 256, 0, stream>>>(btot, bbase, NBKT, E);
    part_scatter<<<NBLK, 256, 0, stream>>>(ei, bcountT, bbase, sorted, NBKT, NBLK, E);
    bucket_csr<<<NBKT, 512, 0, stream>>>(sorted, bbase, rp, dinv, csr, n, E);

    // ---- all weight transposes in one launch ----
    TAll ta;
    ta.src[0] = pre_w;   ta.K[0] = 128; ta.N[0] = 128;
    ta.src[1] = conv_w[0]; ta.K[1] = 128; ta.N[1] = 128;
    ta.src[2] = conv_w[1]; ta.K[2] = 256; ta.N[2] = 128;
    ta.src[3] = conv_w[2]; ta.K[3] = 384; ta.N[3] = 128;
    ta.src[4] = conv_w[3]; ta.K[4] = 512; ta.N[4] = 128;
    ta.src[5] = post_w1;  ta.K[5] = 640; ta.N[5] = 128;
    ta.src[6] = post_w2;  ta.K[6] = 128; ta.N[6] = 128;
    ta.src[7] = post_w3;  ta.K[7] = 128; ta.N[7] = 256;
    ta.src[8] = post_w4;  ta.K[8] = 256; ta.N[8] = 128;
    ta.cum[0] = 0;
    for (int s = 0; s < 9; ++s) ta.cum[s + 1] = ta.cum[s] + ta.K[s] * ta.N[s];
    const int wtot = ta.cum[9];   // 344064
    transpose_all<<<(wtot + 255) / 256, 256, 0, stream>>>(ta, wt, wtot);

    const int gx = (n + 127) / 128;   // 782
    auto gemm = [&](const bf16* A1, int lda1, int K1, const bf16* A2, int lda2,
                    const bf16* WT, const float* bias, const float* rs,
                    void* C, int ldc, int Ktot, int N, int act, int outf32) {
        dim3 grid(gx, N / 128);
        gemm_bf16<<<grid, 256, 0, stream>>>(A1, lda1, K1, A2, lda2, WT, bias, rs,
                                            C, ldc, n, Ktot, act, outf32);
    };

    const int ggrid = (int)(((long long)n * 64 + 255) / 256);
    for (int l = 0; l < 4; ++l) {
        if (l == 0) {
            fused_pre<<<gx, 256, 0, stream>>>(x, pre_wt, pre_b, c_wt0, dinv,
                                              emb, 512, g, n);
        } else {
            int K = 128 * (l + 1);
            gemm(emb, 512, K, emb, 512, c_wt[l], nullptr, dinv, g, 128, K, 128, 0, 0);
        }
        bf16* out = (l < 3) ? (emb + (size_t)128 * (l + 1)) : h4;
        int ldo = (l < 3) ? 512 : 128;
        gcn_gather<<<ggrid, 256, 0, stream>>>(rp, csr, g, dinv, conv_b[l], out, ldo, n);
    }

    // post_mp: single fused kernel, 512 threads / 128-row tile
    fused_post<<<gx, 512, 0, stream>>>(emb, 512, h4,
                                       p1_wt, post_b1, p2_wt, post_b2,
                                       p3_wt, post_b3, p4_wt, post_b4,
                                       (float*)d_out, n);
}

// Round 14
// 587.485 us; speedup vs baseline: 1.0343x; 1.0343x over previous
//
#include <hip/hip_runtime.h>

// ---------------------------------------------------------------------------
// GeneralGNN: 4-layer GCN (skip='all') + MLP head.
// Round 14: revert fused_post to r12 geometry (64-row/256thr/48KB, 3 blk/CU)
// + T3-minimum 2-phase pipeline on stage-0 (K=640): double-buffered Am/Bls,
// next-tile gloads issued BEFORE current-tile MFMAs, one vmcnt(0)+barrier per
// tile. LDS stays 48KB via overlays (stage0: Bls0|Bls1|Am0|Am1; later:
// H1|Bls|H2, H3 over H1). r13 lesson: intra-block waves share barriers ->
// no overlap; only independent blocks (3/CU) hide drain stalls.
// ---------------------------------------------------------------------------

typedef __bf16 bf16;
typedef __attribute__((ext_vector_type(8))) __bf16 bf16x8;
typedef __attribute__((ext_vector_type(4))) float f32x4;

#define BSHIFT 9                 // bucket = dst >> 9  (512 nodes/bucket)
#define PCHUNK 4096              // edges per partition block

// ---- Pass A: per-(bucket, block) counts; no global atomics ----
__global__ __launch_bounds__(256) void part_count(const int* __restrict__ ei,
                                                  int* __restrict__ bcountT,
                                                  int NBKT, int NBLK, int E) {
    __shared__ int cnt[256];
    const int t = threadIdx.x, blk = blockIdx.x;
    if (t < NBKT) cnt[t] = 0;
    __syncthreads();
    const int base = blk * PCHUNK;
#pragma unroll
    for (int i = 0; i < 16; ++i) {
        int e = base + i * 256 + t;
        if (e < E) atomicAdd(&cnt[ei[E + e] >> BSHIFT], 1);   // LDS atomic
    }
    __syncthreads();
    if (t < NBKT) bcountT[t * NBLK + blk] = cnt[t];
}

// ---- Pass B: per-bucket exclusive scan of its row (across blocks) ----
__global__ __launch_bounds__(256) void part_scanb(int* __restrict__ bcountT,
                                                  int* __restrict__ btot, int NBLK) {
    __shared__ int sums[256];
    const int b = blockIdx.x, t = threadIdx.x;
    int* row = &bcountT[(size_t)b * NBLK];
    const int chunk = (NBLK + 255) / 256;
    const int lo = t * chunk, hi = min(lo + chunk, NBLK);
    int s = 0;
    for (int i = lo; i < hi; ++i) s += row[i];
    sums[t] = s;
    __syncthreads();
#pragma unroll
    for (int off = 1; off < 256; off <<= 1) {
        int u = (t >= off) ? sums[t - off] : 0;
        __syncthreads();
        sums[t] += u;
        __syncthreads();
    }
    int run = sums[t] - s;
    for (int i = lo; i < hi; ++i) { int c = row[i]; row[i] = run; run += c; }
    if (t == 255) btot[b] = sums[255];
}

// ---- Pass B2: bucket bases (exclusive scan of btot); bbase[NBKT] = E ----
__global__ __launch_bounds__(256) void part_scant(const int* __restrict__ btot,
                                                  int* __restrict__ bbase, int NBKT, int E) {
    __shared__ int sums[256];
    const int t = threadIdx.x;
    int s = (t < NBKT) ? btot[t] : 0;
    sums[t] = s;
    __syncthreads();
#pragma unroll
    for (int off = 1; off < 256; off <<= 1) {
        int u = (t >= off) ? sums[t - off] : 0;
        __syncthreads();
        sums[t] += u;
        __syncthreads();
    }
    if (t < NBKT) bbase[t] = sums[t] - s;
    if (t == 0) bbase[NBKT] = E;
}

// ---- Pass C: scatter edges to bucket-sorted order ----
__global__ __launch_bounds__(256) void part_scatter(const int* __restrict__ ei,
                                                    const int* __restrict__ bcountT,
                                                    const int* __restrict__ bbase,
                                                    int2* __restrict__ sorted,
                                                    int NBKT, int NBLK, int E) {
    __shared__ int cur[256];
    const int t = threadIdx.x, blk = blockIdx.x;
    if (t < NBKT) cur[t] = bbase[t] + bcountT[(size_t)t * NBLK + blk];
    __syncthreads();
    const int base = blk * PCHUNK;
#pragma unroll
    for (int i = 0; i < 16; ++i) {
        int e = base + i * 256 + t;
        if (e < E) {
            int src = ei[e], dst = ei[E + e];
            int pos = atomicAdd(&cur[dst >> BSHIFT], 1);      // LDS atomic
            sorted[pos] = make_int2(src, dst);
        }
    }
}

// ---- Pass D: per-bucket CSR rows + rp + dinv (all traffic L2-local) ----
__global__ __launch_bounds__(512) void bucket_csr(const int2* __restrict__ sorted,
                                                  const int* __restrict__ bbase,
                                                  int* __restrict__ rp,
                                                  float* __restrict__ dinv,
                                                  int* __restrict__ csr,
                                                  int n, int E) {
    __shared__ int cnt[512];
    __shared__ int cur[512];
    const int b = blockIdx.x, t = threadIdx.x;
    const int nb0 = b << BSHIFT;
    const int lo = bbase[b], hi = bbase[b + 1];
    cnt[t] = 0;
    __syncthreads();
    for (int k = lo + t; k < hi; k += 512)
        atomicAdd(&cnt[sorted[k].y - nb0], 1);                // LDS atomic
    __syncthreads();
    const int own = cnt[t];
    cur[t] = own;
    __syncthreads();
#pragma unroll
    for (int off = 1; off < 512; off <<= 1) {
        int u = (t >= off) ? cur[t - off] : 0;
        __syncthreads();
        cur[t] += u;
        __syncthreads();
    }
    const int excl = cur[t] - own;
    const int node = nb0 + t;
    if (node < n) {
        rp[node] = lo + excl;
        dinv[node] = rsqrtf((float)(own + 1));
    }
    if (b == 0 && t == 0) rp[n] = E;
    __syncthreads();
    cur[t] = excl;
    __syncthreads();
    for (int k = lo + t; k < hi; k += 512) {
        int2 e = sorted[k];
        int pos = atomicAdd(&cur[e.y - nb0], 1);              // LDS atomic
        csr[lo + pos] = e.x;
    }
}

// ---------------- weight transposes (one launch) ----------------
struct TAll {
    const float* src[9];
    int cum[10];
    int N[9];
    int K[9];
};
__global__ __launch_bounds__(256) void transpose_all(TAll d, bf16* __restrict__ wt, int total) {
    int idx = blockIdx.x * 256 + threadIdx.x;
    if (idx >= total) return;
    int seg = 0;
#pragma unroll
    for (int s = 1; s < 9; ++s) if (idx >= d.cum[s]) seg = s;
    int local = idx - d.cum[seg];
    int N = d.N[seg], K = d.K[seg];
    int k = local / N;
    int nn = local - k * N;
    wt[d.cum[seg] + (size_t)nn * K + k] = (bf16)d.src[seg][local];
}

// ---------------- LDS-layout helpers ----------------
__device__ __forceinline__ void stash_lds(char* H, int ktStride, int r, int c, float v) {
    int kt = c >> 6, w = c & 63;
    int byte = kt * ktStride + r * 128 + (((w >> 3) ^ (r & 7)) * 8 + (w & 7)) * 2;
    *(bf16*)(H + byte) = (bf16)v;
}
__device__ __forceinline__ bf16x8 afrag_lds(const char* H, int ktStride, int kt, int r, int ks, int lane) {
    int ch = (ks * 4 + (lane >> 4)) ^ (r & 7);
    return *(const bf16x8*)(H + kt * ktStride + r * 128 + ch * 16);
}

// ---------------- bf16 MFMA GEMM (conv1..3) ----------------
__global__ __launch_bounds__(256) void gemm_bf16(
    const bf16* __restrict__ A1, int lda1, int K1,
    const bf16* __restrict__ A2, int lda2,
    const bf16* __restrict__ WT,
    const float* __restrict__ bias,
    const float* __restrict__ rowscale,
    void* __restrict__ Cout, int ldc, int M, int Ktot,
    int act, int outf32)
{
    __shared__ bf16 Als[128 * 64];
    __shared__ bf16 Bls[128 * 64];

    const int t = threadIdx.x;
    const int lane = t & 63;
    const int wid = t >> 6;
    const int wm = wid >> 1, wn = wid & 1;
    const int row0 = blockIdx.x * 128;
    const int col0 = blockIdx.y * 128;
    const int nt = Ktot >> 6;

    f32x4 acc[4][4];
#pragma unroll
    for (int mf = 0; mf < 4; ++mf)
#pragma unroll
        for (int nf = 0; nf < 4; ++nf) {
            f32x4 z = {0.f, 0.f, 0.f, 0.f};
            acc[mf][nf] = z;
        }

    int srow[4], scs[4];
#pragma unroll
    for (int i = 0; i < 4; ++i) {
        int ch = wid * 64 + i * 256 + lane;
        int row = ch >> 3, c = ch & 7;
        srow[i] = row;
        scs[i] = (c ^ (row & 7)) * 8;
    }

    for (int kt = 0; kt < nt; ++kt) {
        const int k0 = kt * 64;
        const bf16* Ap; int lda_, kk;
        if (k0 < K1) { Ap = A1; lda_ = lda1; kk = k0; }
        else         { Ap = A2; lda_ = lda2; kk = k0 - K1; }

        __syncthreads();
#pragma unroll
        for (int i = 0; i < 4; ++i) {
            int grow = row0 + srow[i]; if (grow >= M) grow = M - 1;
            const bf16* ga = &Ap[(size_t)grow * lda_ + kk + scs[i]];
            const bf16* gb = &WT[(size_t)(col0 + srow[i]) * Ktot + k0 + scs[i]];
            bf16* la = &Als[(size_t)(wid * 64 + i * 256) * 8];
            bf16* lb = &Bls[(size_t)(wid * 64 + i * 256) * 8];
            __builtin_amdgcn_global_load_lds(
                (const __attribute__((address_space(1))) void*)ga,
                (__attribute__((address_space(3))) void*)la, 16, 0, 0);
            __builtin_amdgcn_global_load_lds(
                (const __attribute__((address_space(1))) void*)gb,
                (__attribute__((address_space(3))) void*)lb, 16, 0, 0);
        }
        asm volatile("s_waitcnt vmcnt(0)" ::: "memory");
        __syncthreads();

#pragma unroll
        for (int ks = 0; ks < 2; ++ks) {
            bf16x8 af[4], bfr[4];
#pragma unroll
            for (int mf = 0; mf < 4; ++mf) {
                int r = wm * 64 + mf * 16 + (lane & 15);
                int ch = (ks * 4 + (lane >> 4)) ^ (r & 7);
                af[mf] = *(const bf16x8*)((const char*)Als + r * 128 + ch * 16);
            }
#pragma unroll
            for (int nf = 0; nf < 4; ++nf) {
                int r = wn * 64 + nf * 16 + (lane & 15);
                int ch = (ks * 4 + (lane >> 4)) ^ (r & 7);
                bfr[nf] = *(const bf16x8*)((const char*)Bls + r * 128 + ch * 16);
            }
#pragma unroll
            for (int mf = 0; mf < 4; ++mf)
#pragma unroll
                for (int nf = 0; nf < 4; ++nf)
                    acc[mf][nf] = __builtin_amdgcn_mfma_f32_16x16x32_bf16(
                        af[mf], bfr[nf], acc[mf][nf], 0, 0, 0);
        }
    }

#pragma unroll
    for (int mf = 0; mf < 4; ++mf) {
        int rbase = row0 + wm * 64 + mf * 16 + (lane >> 4) * 4;
#pragma unroll
        for (int nf = 0; nf < 4; ++nf) {
            int gcol = col0 + wn * 64 + nf * 16 + (lane & 15);
            float bv = bias ? bias[gcol] : 0.f;
#pragma unroll
            for (int i = 0; i < 4; ++i) {
                int grow = rbase + i;
                if (grow >= M) continue;
                float v = acc[mf][nf][i];
                if (rowscale) v *= rowscale[grow];
                v += bv;
                if (act == 1) v = fmaxf(v, 0.f);
                else if (act == 2) v = v > 0.f ? v : 0.1f * v;
                if (outf32) ((float*)Cout)[(size_t)grow * ldc + gcol] = v;
                else        ((bf16*)Cout)[(size_t)grow * ldc + gcol] = (bf16)v;
            }
        }
    }
}

// ---------------- fused_pre: emb = x@W0+b0 ; g = dinv*(emb@Wc0) ----------------
__global__ __launch_bounds__(256) void fused_pre(
    const float* __restrict__ x,
    const bf16* __restrict__ preWT,
    const float* __restrict__ pre_b,
    const bf16* __restrict__ c0WT,
    const float* __restrict__ dinv,
    bf16* __restrict__ emb, int lde,
    bf16* __restrict__ g, int M)
{
    __shared__ char lds[49152];
    bf16* Hbuf = (bf16*)lds;
    bf16* Bls  = (bf16*)(lds + 32768);
    bf16* Als  = Hbuf;

    const int t = threadIdx.x;
    const int lane = t & 63;
    const int wid = t >> 6;
    const int wm = wid >> 1, wn = wid & 1;
    const int row0 = blockIdx.x * 128;

    int srow[4], scs[4];
#pragma unroll
    for (int i = 0; i < 4; ++i) {
        int ch = wid * 64 + i * 256 + lane;
        int row = ch >> 3, c = ch & 7;
        srow[i] = row;
        scs[i] = (c ^ (row & 7)) * 8;
    }

    f32x4 acc[4][4];
#pragma unroll
    for (int mf = 0; mf < 4; ++mf)
#pragma unroll
        for (int nf = 0; nf < 4; ++nf) { f32x4 z = {0,0,0,0}; acc[mf][nf] = z; }

    for (int kt = 0; kt < 2; ++kt) {
        __syncthreads();
#pragma unroll
        for (int i = 0; i < 4; ++i) {
            int grow = row0 + srow[i]; if (grow >= M) grow = M - 1;
            const float* gx = &x[(size_t)grow * 128 + kt * 64 + scs[i]];
            float4 f0 = *(const float4*)gx;
            float4 f1 = *(const float4*)(gx + 4);
            bf16x8 av = {(bf16)f0.x, (bf16)f0.y, (bf16)f0.z, (bf16)f0.w,
                         (bf16)f1.x, (bf16)f1.y, (bf16)f1.z, (bf16)f1.w};
            *(bf16x8*)((char*)Als + (size_t)(wid * 64 + i * 256 + lane) * 16) = av;
            const bf16* gb = &preWT[(size_t)srow[i] * 128 + kt * 64 + scs[i]];
            bf16* lb = &Bls[(size_t)(wid * 64 + i * 256) * 8];
            __builtin_amdgcn_global_load_lds(
                (const __attribute__((address_space(1))) void*)gb,
                (__attribute__((address_space(3))) void*)lb, 16, 0, 0);
        }
        asm volatile("s_waitcnt vmcnt(0)" ::: "memory");
        __syncthreads();
#pragma unroll
        for (int ks = 0; ks < 2; ++ks) {
            bf16x8 af[4], bfr[4];
#pragma unroll
            for (int mf = 0; mf < 4; ++mf) {
                int r = wm * 64 + mf * 16 + (lane & 15);
                int ch = (ks * 4 + (lane >> 4)) ^ (r & 7);
                af[mf] = *(const bf16x8*)((const char*)Als + r * 128 + ch * 16);
            }
#pragma unroll
            for (int nf = 0; nf < 4; ++nf) {
                int r = wn * 64 + nf * 16 + (lane & 15);
                int ch = (ks * 4 + (lane >> 4)) ^ (r & 7);
                bfr[nf] = *(const bf16x8*)((const char*)Bls + r * 128 + ch * 16);
            }
#pragma unroll
            for (int mf = 0; mf < 4; ++mf)
#pragma unroll
                for (int nf = 0; nf < 4; ++nf)
                    acc[mf][nf] = __builtin_amdgcn_mfma_f32_16x16x32_bf16(
                        af[mf], bfr[nf], acc[mf][nf], 0, 0, 0);
        }
    }
    __syncthreads();

#pragma unroll
    for (int mf = 0; mf < 4; ++mf) {
        int rl = wm * 64 + mf * 16 + (lane >> 4) * 4;
#pragma unroll
        for (int nf = 0; nf < 4; ++nf) {
            int c = wn * 64 + nf * 16 + (lane & 15);
            float bv = pre_b[c];
#pragma unroll
            for (int i = 0; i < 4; ++i) {
                int r = rl + i;
                float v = acc[mf][nf][i] + bv;
                stash_lds((char*)Hbuf, 16384, r, c, v);
                int grow = row0 + r;
                if (grow < M) emb[(size_t)grow * lde + c] = (bf16)v;
            }
        }
    }

#pragma unroll
    for (int mf = 0; mf < 4; ++mf)
#pragma unroll
        for (int nf = 0; nf < 4; ++nf) { f32x4 z = {0,0,0,0}; acc[mf][nf] = z; }

    for (int kt = 0; kt < 2; ++kt) {
        __syncthreads();
#pragma unroll
        for (int i = 0; i < 4; ++i) {
            const bf16* gb = &c0WT[(size_t)srow[i] * 128 + kt * 64 + scs[i]];
            bf16* lb = &Bls[(size_t)(wid * 64 + i * 256) * 8];
            __builtin_amdgcn_global_load_lds(
                (const __attribute__((address_space(1))) void*)gb,
                (__attribute__((address_space(3))) void*)lb, 16, 0, 0);
        }
        asm volatile("s_waitcnt vmcnt(0)" ::: "memory");
        __syncthreads();
#pragma unroll
        for (int ks = 0; ks < 2; ++ks) {
            bf16x8 af[4], bfr[4];
#pragma unroll
            for (int mf = 0; mf < 4; ++mf) {
                int r = wm * 64 + mf * 16 + (lane & 15);
                af[mf] = afrag_lds((const char*)Hbuf, 16384, kt, r, ks, lane);
            }
#pragma unroll
            for (int nf = 0; nf < 4; ++nf) {
                int r = wn * 64 + nf * 16 + (lane & 15);
                int ch = (ks * 4 + (lane >> 4)) ^ (r & 7);
                bfr[nf] = *(const bf16x8*)((const char*)Bls + r * 128 + ch * 16);
            }
#pragma unroll
            for (int mf = 0; mf < 4; ++mf)
#pragma unroll
                for (int nf = 0; nf < 4; ++nf)
                    acc[mf][nf] = __builtin_amdgcn_mfma_f32_16x16x32_bf16(
                        af[mf], bfr[nf], acc[mf][nf], 0, 0, 0);
        }
    }

#pragma unroll
    for (int mf = 0; mf < 4; ++mf) {
        int rbase = row0 + wm * 64 + mf * 16 + (lane >> 4) * 4;
#pragma unroll
        for (int nf = 0; nf < 4; ++nf) {
            int c = wn * 64 + nf * 16 + (lane & 15);
#pragma unroll
            for (int i = 0; i < 4; ++i) {
                int grow = rbase + i;
                if (grow >= M) continue;
                g[(size_t)grow * 128 + c] = (bf16)(acc[mf][nf][i] * dinv[grow]);
            }
        }
    }
}

// ---------------- fused_post: [emb|h4] -> h1 -> h2 -> h3 -> out ----------------
// 64-row tile, 256 thr, 4 waves (2Mx2N), per-wave 32x64, acc[2][4]. LDS 48KB.
// stage-0 (K=640) 2-phase pipelined: Bls0@0 Bls1@16K Am0@32K Am1@40K; next
// tile's 6 gloads issued before current tile's MFMAs; vmcnt(0)+barrier per kt.
// After stage 0: H1@0 (16K), Bls@16K, H2@32K (16K), H3 overlays H1.
__global__ __launch_bounds__(256) void fused_post(
    const bf16* __restrict__ emb, int lde,
    const bf16* __restrict__ h4,     // n x 128
    const bf16* __restrict__ W1T,    // [128][640]
    const float* __restrict__ b1,
    const bf16* __restrict__ W2T,    // [128][128]
    const float* __restrict__ b2,
    const bf16* __restrict__ W3T,    // [256][128]
    const float* __restrict__ b3,
    const bf16* __restrict__ W4T,    // [128][256]
    const float* __restrict__ b4,
    float* __restrict__ out, int M)
{
    __shared__ char lds[49152];
    bf16* H1  = (bf16*)lds;              // 16K (overlays Bls0; post-stage0)
    bf16* H3  = (bf16*)lds;              // overlays H1 (dead after stage 1)
    bf16* Bls = (bf16*)(lds + 16384);    // 16K (stages 1-3; = Bls1 region)
    bf16* H2  = (bf16*)(lds + 32768);    // 16K (overlays Am0+Am1)

    const int t = threadIdx.x;
    const int lane = t & 63;
    const int wid = t >> 6;
    const int wm = wid >> 1, wn = wid & 1;
    const int row0 = blockIdx.x * 64;

    int srow[4], scs[4];
#pragma unroll
    for (int i = 0; i < 4; ++i) {
        int ch = wid * 64 + i * 256 + lane;
        int row = ch >> 3, c = ch & 7;
        srow[i] = row;
        scs[i] = (c ^ (row & 7)) * 8;
    }

    f32x4 acc[2][4], acc3[2][4];
#pragma unroll
    for (int mf = 0; mf < 2; ++mf)
#pragma unroll
        for (int nf = 0; nf < 4; ++nf) {
            f32x4 z = {0,0,0,0};
            acc[mf][nf] = z;
            acc3[mf][nf] = z;
        }

    // stage-0 staging: A (64x64 = 512 chunks, 2/thread) + B (128x64, 4/thread)
    auto stage0 = [&](int buf, int kt) {
        const int k0 = kt * 64;
        char* AmB = (char*)lds + 32768 + buf * 8192;
        char* BlB = (char*)lds + buf * 16384;
#pragma unroll
        for (int i = 0; i < 2; ++i) {
            int grow = row0 + srow[i]; if (grow >= M) grow = M - 1;
            const bf16* ga = (k0 < 512)
                ? &emb[(size_t)grow * lde + k0 + scs[i]]
                : &h4[(size_t)grow * 128 + (k0 - 512) + scs[i]];
            bf16* la = (bf16*)AmB + (size_t)(wid * 64 + i * 256) * 8;
            __builtin_amdgcn_global_load_lds(
                (const __attribute__((address_space(1))) void*)ga,
                (__attribute__((address_space(3))) void*)la, 16, 0, 0);
        }
#pragma unroll
        for (int i = 0; i < 4; ++i) {
            const bf16* gb = &W1T[(size_t)srow[i] * 640 + k0 + scs[i]];
            bf16* lb = (bf16*)BlB + (size_t)(wid * 64 + i * 256) * 8;
            __builtin_amdgcn_global_load_lds(
                (const __attribute__((address_space(1))) void*)gb,
                (__attribute__((address_space(3))) void*)lb, 16, 0, 0);
        }
    };

    // ---- stage 0: h1 = LeakyReLU([emb|h4] @ W1T^T + b1), K=640, pipelined ----
    stage0(0, 0);
    asm volatile("s_waitcnt vmcnt(0)" ::: "memory");
    __syncthreads();
    for (int kt = 0; kt < 10; ++kt) {
        const int cur = kt & 1;
        if (kt < 9) stage0(cur ^ 1, kt + 1);     // issue-early: overlaps MFMAs
        const char* AmC = (const char*)lds + 32768 + cur * 8192;
        const char* BlC = (const char*)lds + cur * 16384;
#pragma unroll
        for (int ks = 0; ks < 2; ++ks) {
            bf16x8 af[2], bfr[4];
#pragma unroll
            for (int mf = 0; mf < 2; ++mf) {
                int r = wm * 32 + mf * 16 + (lane & 15);
                int ch = (ks * 4 + (lane >> 4)) ^ (r & 7);
                af[mf] = *(const bf16x8*)(AmC + r * 128 + ch * 16);
            }
#pragma unroll
            for (int nf = 0; nf < 4; ++nf) {
                int r = wn * 64 + nf * 16 + (lane & 15);
                int ch = (ks * 4 + (lane >> 4)) ^ (r & 7);
                bfr[nf] = *(const bf16x8*)(BlC + r * 128 + ch * 16);
            }
#pragma unroll
            for (int mf = 0; mf < 2; ++mf)
#pragma unroll
                for (int nf = 0; nf < 4; ++nf)
                    acc[mf][nf] = __builtin_amdgcn_mfma_f32_16x16x32_bf16(
                        af[mf], bfr[nf], acc[mf][nf], 0, 0, 0);
        }
        asm volatile("s_waitcnt vmcnt(0)" ::: "memory");   // next tile landed
        __syncthreads();                                   // all reads of cur done
    }
    // epilogue 0 -> H1 (LeakyReLU 0.1); region = Bls0 (dead since kt=8 barrier)
#pragma unroll
    for (int mf = 0; mf < 2; ++mf) {
        int rl = wm * 32 + mf * 16 + (lane >> 4) * 4;
#pragma unroll
        for (int nf = 0; nf < 4; ++nf) {
            int c = wn * 64 + nf * 16 + (lane & 15);
            float bv = b1[c];
#pragma unroll
            for (int i = 0; i < 4; ++i) {
                float v = acc[mf][nf][i] + bv;
                v = v > 0.f ? v : 0.1f * v;
                stash_lds((char*)H1, 8192, rl + i, c, v);
            }
        }
    }

    // ---- stage 1: h2 = relu(h1 @ W2T^T + b2) ----
#pragma unroll
    for (int mf = 0; mf < 2; ++mf)
#pragma unroll
        for (int nf = 0; nf < 4; ++nf) { f32x4 z = {0,0,0,0}; acc[mf][nf] = z; }
    for (int kt = 0; kt < 2; ++kt) {
        __syncthreads();   // (kt=0: also covers H1 epilogue writes)
#pragma unroll
        for (int i = 0; i < 4; ++i) {
            const bf16* gb = &W2T[(size_t)srow[i] * 128 + kt * 64 + scs[i]];
            bf16* lb = &Bls[(size_t)(wid * 64 + i * 256) * 8];
            __builtin_amdgcn_global_load_lds(
                (const __attribute__((address_space(1))) void*)gb,
                (__attribute__((address_space(3))) void*)lb, 16, 0, 0);
        }
        asm volatile("s_waitcnt vmcnt(0)" ::: "memory");
        __syncthreads();
#pragma unroll
        for (int ks = 0; ks < 2; ++ks) {
            bf16x8 af[2], bfr[4];
#pragma unroll
            for (int mf = 0; mf < 2; ++mf) {
                int r = wm * 32 + mf * 16 + (lane & 15);
                af[mf] = afrag_lds((const char*)H1, 8192, kt, r, ks, lane);
            }
#pragma unroll
            for (int nf = 0; nf < 4; ++nf) {
                int r = wn * 64 + nf * 16 + (lane & 15);
                int ch = (ks * 4 + (lane >> 4)) ^ (r & 7);
                bfr[nf] = *(const bf16x8*)((const char*)Bls + r * 128 + ch * 16);
            }
#pragma unroll
            for (int mf = 0; mf < 2; ++mf)
#pragma unroll
                for (int nf = 0; nf < 4; ++nf)
                    acc[mf][nf] = __builtin_amdgcn_mfma_f32_16x16x32_bf16(
                        af[mf], bfr[nf], acc[mf][nf], 0, 0, 0);
        }
    }
    __syncthreads();   // all H1 reads complete before H2 write (Am region dead)
    // epilogue 1 -> H2
#pragma unroll
    for (int mf = 0; mf < 2; ++mf) {
        int rl = wm * 32 + mf * 16 + (lane >> 4) * 4;
#pragma unroll
        for (int nf = 0; nf < 4; ++nf) {
            int c = wn * 64 + nf * 16 + (lane & 15);
            float bv = b2[c];
#pragma unroll
            for (int i = 0; i < 4; ++i)
                stash_lds((char*)H2, 8192, rl + i, c, fmaxf(acc[mf][nf][i] + bv, 0.f));
        }
    }

    // ---- halves: h3half = relu(h2 @ W3T^T + b3) ; out += h3half @ W4T^T ----
    for (int hh = 0; hh < 2; ++hh) {
#pragma unroll
        for (int mf = 0; mf < 2; ++mf)
#pragma unroll
            for (int nf = 0; nf < 4; ++nf) { f32x4 z = {0,0,0,0}; acc[mf][nf] = z; }
        // stage 2: acc = H2 @ W3T(half hh)
        for (int kt = 0; kt < 2; ++kt) {
            __syncthreads();
#pragma unroll
            for (int i = 0; i < 4; ++i) {
                const bf16* gb = &W3T[(size_t)(hh * 128 + srow[i]) * 128 + kt * 64 + scs[i]];
                bf16* lb = &Bls[(size_t)(wid * 64 + i * 256) * 8];
                __builtin_amdgcn_global_load_lds(
                    (const __attribute__((address_space(1))) void*)gb,
                    (__attribute__((address_space(3))) void*)lb, 16, 0, 0);
            }
            asm volatile("s_waitcnt vmcnt(0)" ::: "memory");
            __syncthreads();
#pragma unroll
            for (int ks = 0; ks < 2; ++ks) {
                bf16x8 af[2], bfr[4];
#pragma unroll
                for (int mf = 0; mf < 2; ++mf) {
                    int r = wm * 32 + mf * 16 + (lane & 15);
                    af[mf] = afrag_lds((const char*)H2, 8192, kt, r, ks, lane);
                }
#pragma unroll
                for (int nf = 0; nf < 4; ++nf) {
                    int r = wn * 64 + nf * 16 + (lane & 15);
                    int ch = (ks * 4 + (lane >> 4)) ^ (r & 7);
                    bfr[nf] = *(const bf16x8*)((const char*)Bls + r * 128 + ch * 16);
                }
#pragma unroll
                for (int mf = 0; mf < 2; ++mf)
#pragma unroll
                    for (int nf = 0; nf < 4; ++nf)
                        acc[mf][nf] = __builtin_amdgcn_mfma_f32_16x16x32_bf16(
                            af[mf], bfr[nf], acc[mf][nf], 0, 0, 0);
            }
        }
        __syncthreads();   // prev-H3 reads (hh-1 stage 3) done; H1 long dead
        // epilogue 2 -> H3
#pragma unroll
        for (int mf = 0; mf < 2; ++mf) {
            int rl = wm * 32 + mf * 16 + (lane >> 4) * 4;
#pragma unroll
            for (int nf = 0; nf < 4; ++nf) {
                int c = wn * 64 + nf * 16 + (lane & 15);
                float bv = b3[hh * 128 + c];
#pragma unroll
                for (int i = 0; i < 4; ++i)
                    stash_lds((char*)H3, 8192, rl + i, c, fmaxf(acc[mf][nf][i] + bv, 0.f));
            }
        }
        // stage 3: acc3 += H3 @ W4T (k range hh*128 .. +127)
        for (int kt = 0; kt < 2; ++kt) {
            __syncthreads();
#pragma unroll
            for (int i = 0; i < 4; ++i) {
                const bf16* gb = &W4T[(size_t)srow[i] * 256 + hh * 128 + kt * 64 + scs[i]];
                bf16* lb = &Bls[(size_t)(wid * 64 + i * 256) * 8];
                __builtin_amdgcn_global_load_lds(
                    (const __attribute__((address_space(1))) void*)gb,
                    (__attribute__((address_space(3))) void*)lb, 16, 0, 0);
            }
            asm volatile("s_waitcnt vmcnt(0)" ::: "memory");
            __syncthreads();
#pragma unroll
            for (int ks = 0; ks < 2; ++ks) {
                bf16x8 af[2], bfr[4];
#pragma unroll
                for (int mf = 0; mf < 2; ++mf) {
                    int r = wm * 32 + mf * 16 + (lane & 15);
                    af[mf] = afrag_lds((const char*)H3, 8192, kt, r, ks, lane);
                }
#pragma unroll
                for (int nf = 0; nf < 4; ++nf) {
                    int r = wn * 64 + nf * 16 + (lane & 15);
                    int ch = (ks * 4 + (lane >> 4)) ^ (r & 7);
                    bfr[nf] = *(const bf16x8*)((const char*)Bls + r * 128 + ch * 16);
                }
#pragma unroll
                for (int mf = 0; mf < 2; ++mf)
#pragma unroll
                    for (int nf = 0; nf < 4; ++nf)
                        acc3[mf][nf] = __builtin_amdgcn_mfma_f32_16x16x32_bf16(
                            af[mf], bfr[nf], acc3[mf][nf], 0, 0, 0);
            }
        }
    }

    // final epilogue: out = acc3 + b4 (f32)
#pragma unroll
    for (int mf = 0; mf < 2; ++mf) {
        int rbase = row0 + wm * 32 + mf * 16 + (lane >> 4) * 4;
#pragma unroll
        for (int nf = 0; nf < 4; ++nf) {
            int c = wn * 64 + nf * 16 + (lane & 15);
            float bv = b4[c];
#pragma unroll
            for (int i = 0; i < 4; ++i) {
                int grow = rbase + i;
                if (grow < M) out[(size_t)grow * 128 + c] = acc3[mf][nf][i] + bv;
            }
        }
    }
}

// ---------------- fused gather ----------------
__global__ __launch_bounds__(256) void gcn_gather(
    const int* __restrict__ rp, const int* __restrict__ csr,
    const bf16* __restrict__ g, const float* __restrict__ dinv,
    const float* __restrict__ b,
    bf16* __restrict__ out, int ldo, int n)
{
    const int node = (int)(((long long)blockIdx.x * 256 + threadIdx.x) >> 6);
    if (node >= n) return;
    const int lane = threadIdx.x & 63;
    const int grp = lane >> 4;
    const int cc = lane & 15;
    const int start = rp[node];
    const int end = rp[node + 1];

    float acc[8];
#pragma unroll
    for (int j = 0; j < 8; ++j) acc[j] = 0.f;

    int j = start + grp;
    for (; j + 12 < end; j += 16) {
        int s0 = csr[j];
        int s1 = csr[j + 4];
        int s2 = csr[j + 8];
        int s3 = csr[j + 12];
        bf16x8 v0 = *(const bf16x8*)&g[(size_t)s0 * 128 + cc * 8];
        bf16x8 v1 = *(const bf16x8*)&g[(size_t)s1 * 128 + cc * 8];
        bf16x8 v2 = *(const bf16x8*)&g[(size_t)s2 * 128 + cc * 8];
        bf16x8 v3 = *(const bf16x8*)&g[(size_t)s3 * 128 + cc * 8];
#pragma unroll
        for (int jj = 0; jj < 8; ++jj)
            acc[jj] += ((float)v0[jj] + (float)v1[jj]) + ((float)v2[jj] + (float)v3[jj]);
    }
    for (; j < end; j += 4) {
        int s0 = csr[j];
        bf16x8 v0 = *(const bf16x8*)&g[(size_t)s0 * 128 + cc * 8];
#pragma unroll
        for (int jj = 0; jj < 8; ++jj) acc[jj] += (float)v0[jj];
    }
#pragma unroll
    for (int jj = 0; jj < 8; ++jj) {
        acc[jj] += __shfl_xor(acc[jj], 16, 64);
        acc[jj] += __shfl_xor(acc[jj], 32, 64);
    }
    if (grp == 0) {
        bf16x8 sv = *(const bf16x8*)&g[(size_t)node * 128 + cc * 8];
        float s = dinv[node];
        bf16x8 o;
#pragma unroll
        for (int jj = 0; jj < 8; ++jj) {
            float v = fmaf(s, acc[jj] + (float)sv[jj], b[cc * 8 + jj]);
            o[jj] = (bf16)fmaxf(v, 0.f);
        }
        *(bf16x8*)&out[(size_t)node * ldo + cc * 8] = o;
    }
}

// ---------------- launcher ----------------
extern "C" void kernel_launch(void* const* d_in, const int* in_sizes, int n_in,
                              void* d_out, int out_size, void* d_ws, size_t ws_size,
                              hipStream_t stream) {
    const float* x      = (const float*)d_in[0];
    const int*   ei     = (const int*)d_in[1];
    const float* pre_w  = (const float*)d_in[2];
    const float* pre_b  = (const float*)d_in[3];
    const float* conv_w[4] = {(const float*)d_in[4], (const float*)d_in[6],
                              (const float*)d_in[8], (const float*)d_in[10]};
    const float* conv_b[4] = {(const float*)d_in[5], (const float*)d_in[7],
                              (const float*)d_in[9], (const float*)d_in[11]};
    const float* post_w1 = (const float*)d_in[12];
    const float* post_b1 = (const float*)d_in[13];
    const float* post_w2 = (const float*)d_in[14];
    const float* post_b2 = (const float*)d_in[15];
    const float* post_w3 = (const float*)d_in[16];
    const float* post_b3 = (const float*)d_in[17];
    const float* post_w4 = (const float*)d_in[18];
    const float* post_b4 = (const float*)d_in[19];

    const int n = in_sizes[0] / 128;        // 100000
    const int E = in_sizes[1] / 2;          // 1600000
    const int NBKT = (n + 511) >> BSHIFT;   // 196 buckets
    const int NBLK = (E + PCHUNK - 1) / PCHUNK;  // 391 partition blocks

    // ws layout (bytes)
    size_t off = 0;
    bf16* emb  = (bf16*)((char*)d_ws + off); off += (size_t)n * 512 * 2;
    bf16* g    = (bf16*)((char*)d_ws + off); off += (size_t)n * 128 * 2;
    bf16* h4   = (bf16*)((char*)d_ws + off); off += (size_t)n * 128 * 2;
    float* dinv = (float*)((char*)d_ws + off); off += (size_t)n * 4;
    int*   rp   = (int*)((char*)d_ws + off); off += (size_t)(n + 4) * 4;
    int*   csr  = (int*)((char*)d_ws + off); off += (size_t)E * 4;
    int2*  sorted = (int2*)((char*)d_ws + off); off += (size_t)E * 8;
    bf16*  wt   = (bf16*)((char*)d_ws + off); off += (size_t)344064 * 2;
    int*   bcountT = (int*)((char*)d_ws + off); off += (size_t)NBKT * NBLK * 4;
    int*   btot    = (int*)((char*)d_ws + off); off += (size_t)NBKT * 4;
    int*   bbase   = (int*)((char*)d_ws + off); off += (size_t)(NBKT + 1) * 4;
    if (ws_size < off) return;  // diagnostic early-out

    // weight-pool offsets (elements)
    bf16* pre_wt  = wt;            // [128][128]
    bf16* c_wt0   = wt + 16384;
    bf16* c_wt1   = wt + 32768;
    bf16* c_wt2   = wt + 65536;
    bf16* c_wt3   = wt + 114688;
    bf16* p1_wt   = wt + 180224;   // [128][640]
    bf16* p2_wt   = wt + 262144;
    bf16* p3_wt   = wt + 278528;   // [256][128]
    bf16* p4_wt   = wt + 311296;   // [128][256]
    bf16* c_wt[4] = {c_wt0, c_wt1, c_wt2, c_wt3};

    // ---- CSR build: bucket partition (no global atomics) ----
    part_count<<<NBLK, 256, 0, stream>>>(ei, bcountT, NBKT, NBLK, E);
    part_scanb<<<NBKT, 256, 0, stream>>>(bcountT, btot, NBLK);
    part_scant<<<1, 256, 0, stream>>>(btot, bbase, NBKT, E);
    part_scatter<<<NBLK, 256, 0, stream>>>(ei, bcountT, bbase, sorted, NBKT, NBLK, E);
    bucket_csr<<<NBKT, 512, 0, stream>>>(sorted, bbase, rp, dinv, csr, n, E);

    // ---- all weight transposes in one launch ----
    TAll ta;
    ta.src[0] = pre_w;   ta.K[0] = 128; ta.N[0] = 128;
    ta.src[1] = conv_w[0]; ta.K[1] = 128; ta.N[1] = 128;
    ta.src[2] = conv_w[1]; ta.K[2] = 256; ta.N[2] = 128;
    ta.src[3] = conv_w[2]; ta.K[3] = 384; ta.N[3] = 128;
    ta.src[4] = conv_w[3]; ta.K[4] = 512; ta.N[4] = 128;
    ta.src[5] = post_w1;  ta.K[5] = 640; ta.N[5] = 128;
    ta.src[6] = post_w2;  ta.K[6] = 128; ta.N[6] = 128;
    ta.src[7] = post_w3;  ta.K[7] = 128; ta.N[7] = 256;
    ta.src[8] = post_w4;  ta.K[8] = 256; ta.N[8] = 128;
    ta.cum[0] = 0;
    for (int s = 0; s < 9; ++s) ta.cum[s + 1] = ta.cum[s] + ta.K[s] * ta.N[s];
    const int wtot = ta.cum[9];   // 344064
    transpose_all<<<(wtot + 255) / 256, 256, 0, stream>>>(ta, wt, wtot);

    const int gx = (n + 127) / 128;   // 782
    const int gx2 = (n + 63) / 64;    // 1563
    auto gemm = [&](const bf16* A1, int lda1, int K1, const bf16* A2, int lda2,
                    const bf16* WT, const float* bias, const float* rs,
                    void* C, int ldc, int Ktot, int N, int act, int outf32) {
        dim3 grid(gx, N / 128);
        gemm_bf16<<<grid, 256, 0, stream>>>(A1, lda1, K1, A2, lda2, WT, bias, rs,
                                            C, ldc, n, Ktot, act, outf32);
    };

    const int ggrid = (int)(((long long)n * 64 + 255) / 256);
    for (int l = 0; l < 4; ++l) {
        if (l == 0) {
            fused_pre<<<gx, 256, 0, stream>>>(x, pre_wt, pre_b, c_wt0, dinv,
                                              emb, 512, g, n);
        } else {
            int K = 128 * (l + 1);
            gemm(emb, 512, K, emb, 512, c_wt[l], nullptr, dinv, g, 128, K, 128, 0, 0);
        }
        bf16* out = (l < 3) ? (emb + (size_t)128 * (l + 1)) : h4;
        int ldo = (l < 3) ? 512 : 128;
        gcn_gather<<<ggrid, 256, 0, stream>>>(rp, csr, g, dinv, conv_b[l], out, ldo, n);
    }

    // post_mp: single fused kernel (r12 geometry + pipelined stage 0)
    fused_post<<<gx2, 256, 0, stream>>>(emb, 512, h4,
                                        p1_wt, post_b1, p2_wt, post_b2,
                                        p3_wt, post_b3, p4_wt, post_b4,
                                        (float*)d_out, n);
}

// Round 15
// 583.250 us; speedup vs baseline: 1.0418x; 1.0073x over previous
//
#include <hip/hip_runtime.h>

// ---------------------------------------------------------------------------
// GeneralGNN: 4-layer GCN (skip='all') + MLP head.
// Round 15: T14 async-STAGE (reg-staged issue-early / ds_write-late) for
// fused_post stages 1-3 weight tiles. Weight-load L2 latency now hides under
// the PREVIOUS phase's MFMAs instead of stalling at vmcnt(0). Prefetch chain:
// S1K0 (issued at stage-0 exit) -> S1K1 -> S2K0 -> S2K1 -> S3K0 -> S3K1 ->
// (hh=1) S2K0' ... S3K1'. LDS stays 48KB (3 blk/CU); +16 VGPR.
// Everything else identical to round 14.
// ---------------------------------------------------------------------------

typedef __bf16 bf16;
typedef __attribute__((ext_vector_type(8))) __bf16 bf16x8;
typedef __attribute__((ext_vector_type(4))) float f32x4;

#define BSHIFT 9                 // bucket = dst >> 9  (512 nodes/bucket)
#define PCHUNK 4096              // edges per partition block

// ---- Pass A: per-(bucket, block) counts; no global atomics ----
__global__ __launch_bounds__(256) void part_count(const int* __restrict__ ei,
                                                  int* __restrict__ bcountT,
                                                  int NBKT, int NBLK, int E) {
    __shared__ int cnt[256];
    const int t = threadIdx.x, blk = blockIdx.x;
    if (t < NBKT) cnt[t] = 0;
    __syncthreads();
    const int base = blk * PCHUNK;
#pragma unroll
    for (int i = 0; i < 16; ++i) {
        int e = base + i * 256 + t;
        if (e < E) atomicAdd(&cnt[ei[E + e] >> BSHIFT], 1);   // LDS atomic
    }
    __syncthreads();
    if (t < NBKT) bcountT[t * NBLK + blk] = cnt[t];
}

// ---- Pass B: per-bucket exclusive scan of its row (across blocks) ----
__global__ __launch_bounds__(256) void part_scanb(int* __restrict__ bcountT,
                                                  int* __restrict__ btot, int NBLK) {
    __shared__ int sums[256];
    const int b = blockIdx.x, t = threadIdx.x;
    int* row = &bcountT[(size_t)b * NBLK];
    const int chunk = (NBLK + 255) / 256;
    const int lo = t * chunk, hi = min(lo + chunk, NBLK);
    int s = 0;
    for (int i = lo; i < hi; ++i) s += row[i];
    sums[t] = s;
    __syncthreads();
#pragma unroll
    for (int off = 1; off < 256; off <<= 1) {
        int u = (t >= off) ? sums[t - off] : 0;
        __syncthreads();
        sums[t] += u;
        __syncthreads();
    }
    int run = sums[t] - s;
    for (int i = lo; i < hi; ++i) { int c = row[i]; row[i] = run; run += c; }
    if (t == 255) btot[b] = sums[255];
}

// ---- Pass B2: bucket bases (exclusive scan of btot); bbase[NBKT] = E ----
__global__ __launch_bounds__(256) void part_scant(const int* __restrict__ btot,
                                                  int* __restrict__ bbase, int NBKT, int E) {
    __shared__ int sums[256];
    const int t = threadIdx.x;
    int s = (t < NBKT) ? btot[t] : 0;
    sums[t] = s;
    __syncthreads();
#pragma unroll
    for (int off = 1; off < 256; off <<= 1) {
        int u = (t >= off) ? sums[t - off] : 0;
        __syncthreads();
        sums[t] += u;
        __syncthreads();
    }
    if (t < NBKT) bbase[t] = sums[t] - s;
    if (t == 0) bbase[NBKT] = E;
}

// ---- Pass C: scatter edges to bucket-sorted order ----
__global__ __launch_bounds__(256) void part_scatter(const int* __restrict__ ei,
                                                    const int* __restrict__ bcountT,
                                                    const int* __restrict__ bbase,
                                                    int2* __restrict__ sorted,
                                                    int NBKT, int NBLK, int E) {
    __shared__ int cur[256];
    const int t = threadIdx.x, blk = blockIdx.x;
    if (t < NBKT) cur[t] = bbase[t] + bcountT[(size_t)t * NBLK + blk];
    __syncthreads();
    const int base = blk * PCHUNK;
#pragma unroll
    for (int i = 0; i < 16; ++i) {
        int e = base + i * 256 + t;
        if (e < E) {
            int src = ei[e], dst = ei[E + e];
            int pos = atomicAdd(&cur[dst >> BSHIFT], 1);      // LDS atomic
            sorted[pos] = make_int2(src, dst);
        }
    }
}

// ---- Pass D: per-bucket CSR rows + rp + dinv (all traffic L2-local) ----
__global__ __launch_bounds__(512) void bucket_csr(const int2* __restrict__ sorted,
                                                  const int* __restrict__ bbase,
                                                  int* __restrict__ rp,
                                                  float* __restrict__ dinv,
                                                  int* __restrict__ csr,
                                                  int n, int E) {
    __shared__ int cnt[512];
    __shared__ int cur[512];
    const int b = blockIdx.x, t = threadIdx.x;
    const int nb0 = b << BSHIFT;
    const int lo = bbase[b], hi = bbase[b + 1];
    cnt[t] = 0;
    __syncthreads();
    for (int k = lo + t; k < hi; k += 512)
        atomicAdd(&cnt[sorted[k].y - nb0], 1);                // LDS atomic
    __syncthreads();
    const int own = cnt[t];
    cur[t] = own;
    __syncthreads();
#pragma unroll
    for (int off = 1; off < 512; off <<= 1) {
        int u = (t >= off) ? cur[t - off] : 0;
        __syncthreads();
        cur[t] += u;
        __syncthreads();
    }
    const int excl = cur[t] - own;
    const int node = nb0 + t;
    if (node < n) {
        rp[node] = lo + excl;
        dinv[node] = rsqrtf((float)(own + 1));
    }
    if (b == 0 && t == 0) rp[n] = E;
    __syncthreads();
    cur[t] = excl;
    __syncthreads();
    for (int k = lo + t; k < hi; k += 512) {
        int2 e = sorted[k];
        int pos = atomicAdd(&cur[e.y - nb0], 1);              // LDS atomic
        csr[lo + pos] = e.x;
    }
}

// ---------------- weight transposes (one launch) ----------------
struct TAll {
    const float* src[9];
    int cum[10];
    int N[9];
    int K[9];
};
__global__ __launch_bounds__(256) void transpose_all(TAll d, bf16* __restrict__ wt, int total) {
    int idx = blockIdx.x * 256 + threadIdx.x;
    if (idx >= total) return;
    int seg = 0;
#pragma unroll
    for (int s = 1; s < 9; ++s) if (idx >= d.cum[s]) seg = s;
    int local = idx - d.cum[seg];
    int N = d.N[seg], K = d.K[seg];
    int k = local / N;
    int nn = local - k * N;
    wt[d.cum[seg] + (size_t)nn * K + k] = (bf16)d.src[seg][local];
}

// ---------------- LDS-layout helpers ----------------
__device__ __forceinline__ void stash_lds(char* H, int ktStride, int r, int c, float v) {
    int kt = c >> 6, w = c & 63;
    int byte = kt * ktStride + r * 128 + (((w >> 3) ^ (r & 7)) * 8 + (w & 7)) * 2;
    *(bf16*)(H + byte) = (bf16)v;
}
__device__ __forceinline__ bf16x8 afrag_lds(const char* H, int ktStride, int kt, int r, int ks, int lane) {
    int ch = (ks * 4 + (lane >> 4)) ^ (r & 7);
    return *(const bf16x8*)(H + kt * ktStride + r * 128 + ch * 16);
}

// ---------------- bf16 MFMA GEMM (conv1..3) ----------------
__global__ __launch_bounds__(256) void gemm_bf16(
    const bf16* __restrict__ A1, int lda1, int K1,
    const bf16* __restrict__ A2, int lda2,
    const bf16* __restrict__ WT,
    const float* __restrict__ bias,
    const float* __restrict__ rowscale,
    void* __restrict__ Cout, int ldc, int M, int Ktot,
    int act, int outf32)
{
    __shared__ bf16 Als[128 * 64];
    __shared__ bf16 Bls[128 * 64];

    const int t = threadIdx.x;
    const int lane = t & 63;
    const int wid = t >> 6;
    const int wm = wid >> 1, wn = wid & 1;
    const int row0 = blockIdx.x * 128;
    const int col0 = blockIdx.y * 128;
    const int nt = Ktot >> 6;

    f32x4 acc[4][4];
#pragma unroll
    for (int mf = 0; mf < 4; ++mf)
#pragma unroll
        for (int nf = 0; nf < 4; ++nf) {
            f32x4 z = {0.f, 0.f, 0.f, 0.f};
            acc[mf][nf] = z;
        }

    int srow[4], scs[4];
#pragma unroll
    for (int i = 0; i < 4; ++i) {
        int ch = wid * 64 + i * 256 + lane;
        int row = ch >> 3, c = ch & 7;
        srow[i] = row;
        scs[i] = (c ^ (row & 7)) * 8;
    }

    for (int kt = 0; kt < nt; ++kt) {
        const int k0 = kt * 64;
        const bf16* Ap; int lda_, kk;
        if (k0 < K1) { Ap = A1; lda_ = lda1; kk = k0; }
        else         { Ap = A2; lda_ = lda2; kk = k0 - K1; }

        __syncthreads();
#pragma unroll
        for (int i = 0; i < 4; ++i) {
            int grow = row0 + srow[i]; if (grow >= M) grow = M - 1;
            const bf16* ga = &Ap[(size_t)grow * lda_ + kk + scs[i]];
            const bf16* gb = &WT[(size_t)(col0 + srow[i]) * Ktot + k0 + scs[i]];
            bf16* la = &Als[(size_t)(wid * 64 + i * 256) * 8];
            bf16* lb = &Bls[(size_t)(wid * 64 + i * 256) * 8];
            __builtin_amdgcn_global_load_lds(
                (const __attribute__((address_space(1))) void*)ga,
                (__attribute__((address_space(3))) void*)la, 16, 0, 0);
            __builtin_amdgcn_global_load_lds(
                (const __attribute__((address_space(1))) void*)gb,
                (__attribute__((address_space(3))) void*)lb, 16, 0, 0);
        }
        asm volatile("s_waitcnt vmcnt(0)" ::: "memory");
        __syncthreads();

#pragma unroll
        for (int ks = 0; ks < 2; ++ks) {
            bf16x8 af[4], bfr[4];
#pragma unroll
            for (int mf = 0; mf < 4; ++mf) {
                int r = wm * 64 + mf * 16 + (lane & 15);
                int ch = (ks * 4 + (lane >> 4)) ^ (r & 7);
                af[mf] = *(const bf16x8*)((const char*)Als + r * 128 + ch * 16);
            }
#pragma unroll
            for (int nf = 0; nf < 4; ++nf) {
                int r = wn * 64 + nf * 16 + (lane & 15);
                int ch = (ks * 4 + (lane >> 4)) ^ (r & 7);
                bfr[nf] = *(const bf16x8*)((const char*)Bls + r * 128 + ch * 16);
            }
#pragma unroll
            for (int mf = 0; mf < 4; ++mf)
#pragma unroll
                for (int nf = 0; nf < 4; ++nf)
                    acc[mf][nf] = __builtin_amdgcn_mfma_f32_16x16x32_bf16(
                        af[mf], bfr[nf], acc[mf][nf], 0, 0, 0);
        }
    }

#pragma unroll
    for (int mf = 0; mf < 4; ++mf) {
        int rbase = row0 + wm * 64 + mf * 16 + (lane >> 4) * 4;
#pragma unroll
        for (int nf = 0; nf < 4; ++nf) {
            int gcol = col0 + wn * 64 + nf * 16 + (lane & 15);
            float bv = bias ? bias[gcol] : 0.f;
#pragma unroll
            for (int i = 0; i < 4; ++i) {
                int grow = rbase + i;
                if (grow >= M) continue;
                float v = acc[mf][nf][i];
                if (rowscale) v *= rowscale[grow];
                v += bv;
                if (act == 1) v = fmaxf(v, 0.f);
                else if (act == 2) v = v > 0.f ? v : 0.1f * v;
                if (outf32) ((float*)Cout)[(size_t)grow * ldc + gcol] = v;
                else        ((bf16*)Cout)[(size_t)grow * ldc + gcol] = (bf16)v;
            }
        }
    }
}

// ---------------- fused_pre: emb = x@W0+b0 ; g = dinv*(emb@Wc0) ----------------
__global__ __launch_bounds__(256) void fused_pre(
    const float* __restrict__ x,
    const bf16* __restrict__ preWT,
    const float* __restrict__ pre_b,
    const bf16* __restrict__ c0WT,
    const float* __restrict__ dinv,
    bf16* __restrict__ emb, int lde,
    bf16* __restrict__ g, int M)
{
    __shared__ char lds[49152];
    bf16* Hbuf = (bf16*)lds;
    bf16* Bls  = (bf16*)(lds + 32768);
    bf16* Als  = Hbuf;

    const int t = threadIdx.x;
    const int lane = t & 63;
    const int wid = t >> 6;
    const int wm = wid >> 1, wn = wid & 1;
    const int row0 = blockIdx.x * 128;

    int srow[4], scs[4];
#pragma unroll
    for (int i = 0; i < 4; ++i) {
        int ch = wid * 64 + i * 256 + lane;
        int row = ch >> 3, c = ch & 7;
        srow[i] = row;
        scs[i] = (c ^ (row & 7)) * 8;
    }

    f32x4 acc[4][4];
#pragma unroll
    for (int mf = 0; mf < 4; ++mf)
#pragma unroll
        for (int nf = 0; nf < 4; ++nf) { f32x4 z = {0,0,0,0}; acc[mf][nf] = z; }

    for (int kt = 0; kt < 2; ++kt) {
        __syncthreads();
#pragma unroll
        for (int i = 0; i < 4; ++i) {
            int grow = row0 + srow[i]; if (grow >= M) grow = M - 1;
            const float* gx = &x[(size_t)grow * 128 + kt * 64 + scs[i]];
            float4 f0 = *(const float4*)gx;
            float4 f1 = *(const float4*)(gx + 4);
            bf16x8 av = {(bf16)f0.x, (bf16)f0.y, (bf16)f0.z, (bf16)f0.w,
                         (bf16)f1.x, (bf16)f1.y, (bf16)f1.z, (bf16)f1.w};
            *(bf16x8*)((char*)Als + (size_t)(wid * 64 + i * 256 + lane) * 16) = av;
            const bf16* gb = &preWT[(size_t)srow[i] * 128 + kt * 64 + scs[i]];
            bf16* lb = &Bls[(size_t)(wid * 64 + i * 256) * 8];
            __builtin_amdgcn_global_load_lds(
                (const __attribute__((address_space(1))) void*)gb,
                (__attribute__((address_space(3))) void*)lb, 16, 0, 0);
        }
        asm volatile("s_waitcnt vmcnt(0)" ::: "memory");
        __syncthreads();
#pragma unroll
        for (int ks = 0; ks < 2; ++ks) {
            bf16x8 af[4], bfr[4];
#pragma unroll
            for (int mf = 0; mf < 4; ++mf) {
                int r = wm * 64 + mf * 16 + (lane & 15);
                int ch = (ks * 4 + (lane >> 4)) ^ (r & 7);
                af[mf] = *(const bf16x8*)((const char*)Als + r * 128 + ch * 16);
            }
#pragma unroll
            for (int nf = 0; nf < 4; ++nf) {
                int r = wn * 64 + nf * 16 + (lane & 15);
                int ch = (ks * 4 + (lane >> 4)) ^ (r & 7);
                bfr[nf] = *(const bf16x8*)((const char*)Bls + r * 128 + ch * 16);
            }
#pragma unroll
            for (int mf = 0; mf < 4; ++mf)
#pragma unroll
                for (int nf = 0; nf < 4; ++nf)
                    acc[mf][nf] = __builtin_amdgcn_mfma_f32_16x16x32_bf16(
                        af[mf], bfr[nf], acc[mf][nf], 0, 0, 0);
        }
    }
    __syncthreads();

#pragma unroll
    for (int mf = 0; mf < 4; ++mf) {
        int rl = wm * 64 + mf * 16 + (lane >> 4) * 4;
#pragma unroll
        for (int nf = 0; nf < 4; ++nf) {
            int c = wn * 64 + nf * 16 + (lane & 15);
            float bv = pre_b[c];
#pragma unroll
            for (int i = 0; i < 4; ++i) {
                int r = rl + i;
                float v = acc[mf][nf][i] + bv;
                stash_lds((char*)Hbuf, 16384, r, c, v);
                int grow = row0 + r;
                if (grow < M) emb[(size_t)grow * lde + c] = (bf16)v;
            }
        }
    }

#pragma unroll
    for (int mf = 0; mf < 4; ++mf)
#pragma unroll
        for (int nf = 0; nf < 4; ++nf) { f32x4 z = {0,0,0,0}; acc[mf][nf] = z; }

    for (int kt = 0; kt < 2; ++kt) {
        __syncthreads();
#pragma unroll
        for (int i = 0; i < 4; ++i) {
            const bf16* gb = &c0WT[(size_t)srow[i] * 128 + kt * 64 + scs[i]];
            bf16* lb = &Bls[(size_t)(wid * 64 + i * 256) * 8];
            __builtin_amdgcn_global_load_lds(
                (const __attribute__((address_space(1))) void*)gb,
                (__attribute__((address_space(3))) void*)lb, 16, 0, 0);
        }
        asm volatile("s_waitcnt vmcnt(0)" ::: "memory");
        __syncthreads();
#pragma unroll
        for (int ks = 0; ks < 2; ++ks) {
            bf16x8 af[4], bfr[4];
#pragma unroll
            for (int mf = 0; mf < 4; ++mf) {
                int r = wm * 64 + mf * 16 + (lane & 15);
                af[mf] = afrag_lds((const char*)Hbuf, 16384, kt, r, ks, lane);
            }
#pragma unroll
            for (int nf = 0; nf < 4; ++nf) {
                int r = wn * 64 + nf * 16 + (lane & 15);
                int ch = (ks * 4 + (lane >> 4)) ^ (r & 7);
                bfr[nf] = *(const bf16x8*)((const char*)Bls + r * 128 + ch * 16);
            }
#pragma unroll
            for (int mf = 0; mf < 4; ++mf)
#pragma unroll
                for (int nf = 0; nf < 4; ++nf)
                    acc[mf][nf] = __builtin_amdgcn_mfma_f32_16x16x32_bf16(
                        af[mf], bfr[nf], acc[mf][nf], 0, 0, 0);
        }
    }

#pragma unroll
    for (int mf = 0; mf < 4; ++mf) {
        int rbase = row0 + wm * 64 + mf * 16 + (lane >> 4) * 4;
#pragma unroll
        for (int nf = 0; nf < 4; ++nf) {
            int c = wn * 64 + nf * 16 + (lane & 15);
#pragma unroll
            for (int i = 0; i < 4; ++i) {
                int grow = rbase + i;
                if (grow >= M) continue;
                g[(size_t)grow * 128 + c] = (bf16)(acc[mf][nf][i] * dinv[grow]);
            }
        }
    }
}

// ---------------- fused_post: [emb|h4] -> h1 -> h2 -> h3 -> out ----------------
// 64-row tile, 256 thr, 4 waves (2Mx2N), per-wave 32x64, acc[2][4]. LDS 48KB.
// stage-0 (K=640) 2-phase gload_lds pipeline (as r14). Stages 1-3: T14
// reg-staged weights (issue-early into wreg[4], ds_write after barrier).
__global__ __launch_bounds__(256) void fused_post(
    const bf16* __restrict__ emb, int lde,
    const bf16* __restrict__ h4,     // n x 128
    const bf16* __restrict__ W1T,    // [128][640]
    const float* __restrict__ b1,
    const bf16* __restrict__ W2T,    // [128][128]
    const float* __restrict__ b2,
    const bf16* __restrict__ W3T,    // [256][128]
    const float* __restrict__ b3,
    const bf16* __restrict__ W4T,    // [128][256]
    const float* __restrict__ b4,
    float* __restrict__ out, int M)
{
    __shared__ char lds[49152];
    bf16* H1  = (bf16*)lds;              // 16K (overlays Bls0; post-stage0)
    bf16* H3  = (bf16*)lds;              // overlays H1 (dead after stage 1)
    bf16* Bls = (bf16*)(lds + 16384);    // 16K (stages 1-3; = Bls1 region)
    bf16* H2  = (bf16*)(lds + 32768);    // 16K (overlays Am0+Am1)

    const int t = threadIdx.x;
    const int lane = t & 63;
    const int wid = t >> 6;
    const int wm = wid >> 1, wn = wid & 1;
    const int row0 = blockIdx.x * 64;

    int srow[4], scs[4];
#pragma unroll
    for (int i = 0; i < 4; ++i) {
        int ch = wid * 64 + i * 256 + lane;
        int row = ch >> 3, c = ch & 7;
        srow[i] = row;
        scs[i] = (c ^ (row & 7)) * 8;
    }

    f32x4 acc[2][4], acc3[2][4];
#pragma unroll
    for (int mf = 0; mf < 2; ++mf)
#pragma unroll
        for (int nf = 0; nf < 4; ++nf) {
            f32x4 z = {0,0,0,0};
            acc[mf][nf] = z;
            acc3[mf][nf] = z;
        }

    // T14 weight prefetch registers + helpers (stages 1-3)
    bf16x8 wreg[4];
    auto wload = [&](const bf16* W, int ldw, int rowoff, int k0) {
#pragma unroll
        for (int i = 0; i < 4; ++i)
            wreg[i] = *(const bf16x8*)&W[(size_t)(rowoff + srow[i]) * ldw + k0 + scs[i]];
    };
    auto wstore = [&]() {
#pragma unroll
        for (int i = 0; i < 4; ++i)
            *(bf16x8*)((char*)Bls + (size_t)(wid * 64 + i * 256 + lane) * 16) = wreg[i];
    };

    // stage-0 staging: A (64x64 = 512 chunks, 2/thread) + B (128x64, 4/thread)
    auto stage0 = [&](int buf, int kt) {
        const int k0 = kt * 64;
        char* AmB = (char*)lds + 32768 + buf * 8192;
        char* BlB = (char*)lds + buf * 16384;
#pragma unroll
        for (int i = 0; i < 2; ++i) {
            int grow = row0 + srow[i]; if (grow >= M) grow = M - 1;
            const bf16* ga = (k0 < 512)
                ? &emb[(size_t)grow * lde + k0 + scs[i]]
                : &h4[(size_t)grow * 128 + (k0 - 512) + scs[i]];
            bf16* la = (bf16*)AmB + (size_t)(wid * 64 + i * 256) * 8;
            __builtin_amdgcn_global_load_lds(
                (const __attribute__((address_space(1))) void*)ga,
                (__attribute__((address_space(3))) void*)la, 16, 0, 0);
        }
#pragma unroll
        for (int i = 0; i < 4; ++i) {
            const bf16* gb = &W1T[(size_t)srow[i] * 640 + k0 + scs[i]];
            bf16* lb = (bf16*)BlB + (size_t)(wid * 64 + i * 256) * 8;
            __builtin_amdgcn_global_load_lds(
                (const __attribute__((address_space(1))) void*)gb,
                (__attribute__((address_space(3))) void*)lb, 16, 0, 0);
        }
    };

    // ---- stage 0: h1 = LeakyReLU([emb|h4] @ W1T^T + b1), K=640, pipelined ----
    stage0(0, 0);
    asm volatile("s_waitcnt vmcnt(0)" ::: "memory");
    __syncthreads();
    for (int kt = 0; kt < 10; ++kt) {
        const int cur = kt & 1;
        if (kt < 9) stage0(cur ^ 1, kt + 1);     // issue-early: overlaps MFMAs
        const char* AmC = (const char*)lds + 32768 + cur * 8192;
        const char* BlC = (const char*)lds + cur * 16384;
#pragma unroll
        for (int ks = 0; ks < 2; ++ks) {
            bf16x8 af[2], bfr[4];
#pragma unroll
            for (int mf = 0; mf < 2; ++mf) {
                int r = wm * 32 + mf * 16 + (lane & 15);
                int ch = (ks * 4 + (lane >> 4)) ^ (r & 7);
                af[mf] = *(const bf16x8*)(AmC + r * 128 + ch * 16);
            }
#pragma unroll
            for (int nf = 0; nf < 4; ++nf) {
                int r = wn * 64 + nf * 16 + (lane & 15);
                int ch = (ks * 4 + (lane >> 4)) ^ (r & 7);
                bfr[nf] = *(const bf16x8*)(BlC + r * 128 + ch * 16);
            }
#pragma unroll
            for (int mf = 0; mf < 2; ++mf)
#pragma unroll
                for (int nf = 0; nf < 4; ++nf)
                    acc[mf][nf] = __builtin_amdgcn_mfma_f32_16x16x32_bf16(
                        af[mf], bfr[nf], acc[mf][nf], 0, 0, 0);
        }
        asm volatile("s_waitcnt vmcnt(0)" ::: "memory");   // next tile landed
        __syncthreads();                                   // all reads of cur done
    }
    // prefetch S1K0 (W2T kt=0) into regs — hides under epilogue 0
    wload(W2T, 128, 0, 0);
    // epilogue 0 -> H1 (LeakyReLU 0.1); region = Bls0 (dead since kt=8 barrier)
#pragma unroll
    for (int mf = 0; mf < 2; ++mf) {
        int rl = wm * 32 + mf * 16 + (lane >> 4) * 4;
#pragma unroll
        for (int nf = 0; nf < 4; ++nf) {
            int c = wn * 64 + nf * 16 + (lane & 15);
            float bv = b1[c];
#pragma unroll
            for (int i = 0; i < 4; ++i) {
                float v = acc[mf][nf][i] + bv;
                v = v > 0.f ? v : 0.1f * v;
                stash_lds((char*)H1, 8192, rl + i, c, v);
            }
        }
    }

    // ---- stage 1: h2 = relu(h1 @ W2T^T + b2) ----
#pragma unroll
    for (int mf = 0; mf < 2; ++mf)
#pragma unroll
        for (int nf = 0; nf < 4; ++nf) { f32x4 z = {0,0,0,0}; acc[mf][nf] = z; }
    for (int kt = 0; kt < 2; ++kt) {
        __syncthreads();   // kt=0: H1 epilogue + stage0 Bls reads done; kt=1: prev MFMA Bls reads done
        wstore();          // W(kt) regs -> Bls
        if (kt == 0) wload(W2T, 128, 0, 64);     // S1K1
        else         wload(W3T, 128, 0, 0);      // S2K0 (hh=0)
        __syncthreads();
#pragma unroll
        for (int ks = 0; ks < 2; ++ks) {
            bf16x8 af[2], bfr[4];
#pragma unroll
            for (int mf = 0; mf < 2; ++mf) {
                int r = wm * 32 + mf * 16 + (lane & 15);
                af[mf] = afrag_lds((const char*)H1, 8192, kt, r, ks, lane);
            }
#pragma unroll
            for (int nf = 0; nf < 4; ++nf) {
                int r = wn * 64 + nf * 16 + (lane & 15);
                int ch = (ks * 4 + (lane >> 4)) ^ (r & 7);
                bfr[nf] = *(const bf16x8*)((const char*)Bls + r * 128 + ch * 16);
            }
#pragma unroll
            for (int mf = 0; mf < 2; ++mf)
#pragma unroll
                for (int nf = 0; nf < 4; ++nf)
                    acc[mf][nf] = __builtin_amdgcn_mfma_f32_16x16x32_bf16(
                        af[mf], bfr[nf], acc[mf][nf], 0, 0, 0);
        }
    }
    __syncthreads();   // all H1 reads complete before H2 write (Am region dead)
    // epilogue 1 -> H2
#pragma unroll
    for (int mf = 0; mf < 2; ++mf) {
        int rl = wm * 32 + mf * 16 + (lane >> 4) * 4;
#pragma unroll
        for (int nf = 0; nf < 4; ++nf) {
            int c = wn * 64 + nf * 16 + (lane & 15);
            float bv = b2[c];
#pragma unroll
            for (int i = 0; i < 4; ++i)
                stash_lds((char*)H2, 8192, rl + i, c, fmaxf(acc[mf][nf][i] + bv, 0.f));
        }
    }

    // ---- halves: h3half = relu(h2 @ W3T^T + b3) ; out += h3half @ W4T^T ----
    for (int hh = 0; hh < 2; ++hh) {
#pragma unroll
        for (int mf = 0; mf < 2; ++mf)
#pragma unroll
            for (int nf = 0; nf < 4; ++nf) { f32x4 z = {0,0,0,0}; acc[mf][nf] = z; }
        // stage 2: acc = H2 @ W3T(half hh)
        for (int kt = 0; kt < 2; ++kt) {
            __syncthreads();   // prev MFMA Bls reads done (+ H2 epilogue on first entry)
            wstore();          // S2K(kt) for this hh
            if (kt == 0) wload(W3T, 128, hh * 128, 64);       // S2K1
            else         wload(W4T, 256, 0, hh * 128);        // S3K0
            __syncthreads();
#pragma unroll
            for (int ks = 0; ks < 2; ++ks) {
                bf16x8 af[2], bfr[4];
#pragma unroll
                for (int mf = 0; mf < 2; ++mf) {
                    int r = wm * 32 + mf * 16 + (lane & 15);
                    af[mf] = afrag_lds((const char*)H2, 8192, kt, r, ks, lane);
                }
#pragma unroll
                for (int nf = 0; nf < 4; ++nf) {
                    int r = wn * 64 + nf * 16 + (lane & 15);
                    int ch = (ks * 4 + (lane >> 4)) ^ (r & 7);
                    bfr[nf] = *(const bf16x8*)((const char*)Bls + r * 128 + ch * 16);
                }
#pragma unroll
                for (int mf = 0; mf < 2; ++mf)
#pragma unroll
                    for (int nf = 0; nf < 4; ++nf)
                        acc[mf][nf] = __builtin_amdgcn_mfma_f32_16x16x32_bf16(
                            af[mf], bfr[nf], acc[mf][nf], 0, 0, 0);
            }
        }
        __syncthreads();   // prev-H3 reads (hh-1 stage 3) done; H1 long dead
        // epilogue 2 -> H3
#pragma unroll
        for (int mf = 0; mf < 2; ++mf) {
            int rl = wm * 32 + mf * 16 + (lane >> 4) * 4;
#pragma unroll
            for (int nf = 0; nf < 4; ++nf) {
                int c = wn * 64 + nf * 16 + (lane & 15);
                float bv = b3[hh * 128 + c];
#pragma unroll
                for (int i = 0; i < 4; ++i)
                    stash_lds((char*)H3, 8192, rl + i, c, fmaxf(acc[mf][nf][i] + bv, 0.f));
            }
        }
        // stage 3: acc3 += H3 @ W4T (k range hh*128 .. +127)
        for (int kt = 0; kt < 2; ++kt) {
            __syncthreads();   // prev MFMA Bls reads + H3 epilogue done
            wstore();          // S3K(kt)
            if (kt == 0) wload(W4T, 256, 0, hh * 128 + 64);   // S3K1
            else if (hh == 0) wload(W3T, 128, 128, 0);        // S2K0 (hh=1)
            __syncthreads();
#pragma unroll
            for (int ks = 0; ks < 2; ++ks) {
                bf16x8 af[2], bfr[4];
#pragma unroll
                for (int mf = 0; mf < 2; ++mf) {
                    int r = wm * 32 + mf * 16 + (lane & 15);
                    af[mf] = afrag_lds((const char*)H3, 8192, kt, r, ks, lane);
                }
#pragma unroll
                for (int nf = 0; nf < 4; ++nf) {
                    int r = wn * 64 + nf * 16 + (lane & 15);
                    int ch = (ks * 4 + (lane >> 4)) ^ (r & 7);
                    bfr[nf] = *(const bf16x8*)((const char*)Bls + r * 128 + ch * 16);
                }
#pragma unroll
                for (int mf = 0; mf < 2; ++mf)
#pragma unroll
                    for (int nf = 0; nf < 4; ++nf)
                        acc3[mf][nf] = __builtin_amdgcn_mfma_f32_16x16x32_bf16(
                            af[mf], bfr[nf], acc3[mf][nf], 0, 0, 0);
            }
        }
    }

    // final epilogue: out = acc3 + b4 (f32)
#pragma unroll
    for (int mf = 0; mf < 2; ++mf) {
        int rbase = row0 + wm * 32 + mf * 16 + (lane >> 4) * 4;
#pragma unroll
        for (int nf = 0; nf < 4; ++nf) {
            int c = wn * 64 + nf * 16 + (lane & 15);
            float bv = b4[c];
#pragma unroll
            for (int i = 0; i < 4; ++i) {
                int grow = rbase + i;
                if (grow < M) out[(size_t)grow * 128 + c] = acc3[mf][nf][i] + bv;
            }
        }
    }
}

// ---------------- fused gather ----------------
__global__ __launch_bounds__(256) void gcn_gather(
    const int* __restrict__ rp, const int* __restrict__ csr,
    const bf16* __restrict__ g, const float* __restrict__ dinv,
    const float* __restrict__ b,
    bf16* __restrict__ out, int ldo, int n)
{
    const int node = (int)(((long long)blockIdx.x * 256 + threadIdx.x) >> 6);
    if (node >= n) return;
    const int lane = threadIdx.x & 63;
    const int grp = lane >> 4;
    const int cc = lane & 15;
    const int start = rp[node];
    const int end = rp[node + 1];

    float acc[8];
#pragma unroll
    for (int j = 0; j < 8; ++j) acc[j] = 0.f;

    int j = start + grp;
    for (; j + 12 < end; j += 16) {
        int s0 = csr[j];
        int s1 = csr[j + 4];
        int s2 = csr[j + 8];
        int s3 = csr[j + 12];
        bf16x8 v0 = *(const bf16x8*)&g[(size_t)s0 * 128 + cc * 8];
        bf16x8 v1 = *(const bf16x8*)&g[(size_t)s1 * 128 + cc * 8];
        bf16x8 v2 = *(const bf16x8*)&g[(size_t)s2 * 128 + cc * 8];
        bf16x8 v3 = *(const bf16x8*)&g[(size_t)s3 * 128 + cc * 8];
#pragma unroll
        for (int jj = 0; jj < 8; ++jj)
            acc[jj] += ((float)v0[jj] + (float)v1[jj]) + ((float)v2[jj] + (float)v3[jj]);
    }
    for (; j < end; j += 4) {
        int s0 = csr[j];
        bf16x8 v0 = *(const bf16x8*)&g[(size_t)s0 * 128 + cc * 8];
#pragma unroll
        for (int jj = 0; jj < 8; ++jj) acc[jj] += (float)v0[jj];
    }
#pragma unroll
    for (int jj = 0; jj < 8; ++jj) {
        acc[jj] += __shfl_xor(acc[jj], 16, 64);
        acc[jj] += __shfl_xor(acc[jj], 32, 64);
    }
    if (grp == 0) {
        bf16x8 sv = *(const bf16x8*)&g[(size_t)node * 128 + cc * 8];
        float s = dinv[node];
        bf16x8 o;
#pragma unroll
        for (int jj = 0; jj < 8; ++jj) {
            float v = fmaf(s, acc[jj] + (float)sv[jj], b[cc * 8 + jj]);
            o[jj] = (bf16)fmaxf(v, 0.f);
        }
        *(bf16x8*)&out[(size_t)node * ldo + cc * 8] = o;
    }
}

// ---------------- launcher ----------------
extern "C" void kernel_launch(void* const* d_in, const int* in_sizes, int n_in,
                              void* d_out, int out_size, void* d_ws, size_t ws_size,
                              hipStream_t stream) {
    const float* x      = (const float*)d_in[0];
    const int*   ei     = (const int*)d_in[1];
    const float* pre_w  = (const float*)d_in[2];
    const float* pre_b  = (const float*)d_in[3];
    const float* conv_w[4] = {(const float*)d_in[4], (const float*)d_in[6],
                              (const float*)d_in[8], (const float*)d_in[10]};
    const float* conv_b[4] = {(const float*)d_in[5], (const float*)d_in[7],
                              (const float*)d_in[9], (const float*)d_in[11]};
    const float* post_w1 = (const float*)d_in[12];
    const float* post_b1 = (const float*)d_in[13];
    const float* post_w2 = (const float*)d_in[14];
    const float* post_b2 = (const float*)d_in[15];
    const float* post_w3 = (const float*)d_in[16];
    const float* post_b3 = (const float*)d_in[17];
    const float* post_w4 = (const float*)d_in[18];
    const float* post_b4 = (const float*)d_in[19];

    const int n = in_sizes[0] / 128;        // 100000
    const int E = in_sizes[1] / 2;          // 1600000
    const int NBKT = (n + 511) >> BSHIFT;   // 196 buckets
    const int NBLK = (E + PCHUNK - 1) / PCHUNK;  // 391 partition blocks

    // ws layout (bytes)
    size_t off = 0;
    bf16* emb  = (bf16*)((char*)d_ws + off); off += (size_t)n * 512 * 2;
    bf16* g    = (bf16*)((char*)d_ws + off); off += (size_t)n * 128 * 2;
    bf16* h4   = (bf16*)((char*)d_ws + off); off += (size_t)n * 128 * 2;
    float* dinv = (float*)((char*)d_ws + off); off += (size_t)n * 4;
    int*   rp   = (int*)((char*)d_ws + off); off += (size_t)(n + 4) * 4;
    int*   csr  = (int*)((char*)d_ws + off); off += (size_t)E * 4;
    int2*  sorted = (int2*)((char*)d_ws + off); off += (size_t)E * 8;
    bf16*  wt   = (bf16*)((char*)d_ws + off); off += (size_t)344064 * 2;
    int*   bcountT = (int*)((char*)d_ws + off); off += (size_t)NBKT * NBLK * 4;
    int*   btot    = (int*)((char*)d_ws + off); off += (size_t)NBKT * 4;
    int*   bbase   = (int*)((char*)d_ws + off); off += (size_t)(NBKT + 1) * 4;
    if (ws_size < off) return;  // diagnostic early-out

    // weight-pool offsets (elements)
    bf16* pre_wt  = wt;            // [128][128]
    bf16* c_wt0   = wt + 16384;
    bf16* c_wt1   = wt + 32768;
    bf16* c_wt2   = wt + 65536;
    bf16* c_wt3   = wt + 114688;
    bf16* p1_wt   = wt + 180224;   // [128][640]
    bf16* p2_wt   = wt + 262144;
    bf16* p3_wt   = wt + 278528;   // [256][128]
    bf16* p4_wt   = wt + 311296;   // [128][256]
    bf16* c_wt[4] = {c_wt0, c_wt1, c_wt2, c_wt3};

    // ---- CSR build: bucket partition (no global atomics) ----
    part_count<<<NBLK, 256, 0, stream>>>(ei, bcountT, NBKT, NBLK, E);
    part_scanb<<<NBKT, 256, 0, stream>>>(bcountT, btot, NBLK);
    part_scant<<<1, 256, 0, stream>>>(btot, bbase, NBKT, E);
    part_scatter<<<NBLK, 256, 0, stream>>>(ei, bcountT, bbase, sorted, NBKT, NBLK, E);
    bucket_csr<<<NBKT, 512, 0, stream>>>(sorted, bbase, rp, dinv, csr, n, E);

    // ---- all weight transposes in one launch ----
    TAll ta;
    ta.src[0] = pre_w;   ta.K[0] = 128; ta.N[0] = 128;
    ta.src[1] = conv_w[0]; ta.K[1] = 128; ta.N[1] = 128;
    ta.src[2] = conv_w[1]; ta.K[2] = 256; ta.N[2] = 128;
    ta.src[3] = conv_w[2]; ta.K[3] = 384; ta.N[3] = 128;
    ta.src[4] = conv_w[3]; ta.K[4] = 512; ta.N[4] = 128;
    ta.src[5] = post_w1;  ta.K[5] = 640; ta.N[5] = 128;
    ta.src[6] = post_w2;  ta.K[6] = 128; ta.N[6] = 128;
    ta.src[7] = post_w3;  ta.K[7] = 128; ta.N[7] = 256;
    ta.src[8] = post_w4;  ta.K[8] = 256; ta.N[8] = 128;
    ta.cum[0] = 0;
    for (int s = 0; s < 9; ++s) ta.cum[s + 1] = ta.cum[s] + ta.K[s] * ta.N[s];
    const int wtot = ta.cum[9];   // 344064
    transpose_all<<<(wtot + 255) / 256, 256, 0, stream>>>(ta, wt, wtot);

    const int gx = (n + 127) / 128;   // 782
    const int gx2 = (n + 63) / 64;    // 1563
    auto gemm = [&](const bf16* A1, int lda1, int K1, const bf16* A2, int lda2,
                    const bf16* WT, const float* bias, const float* rs,
                    void* C, int ldc, int Ktot, int N, int act, int outf32) {
        dim3 grid(gx, N / 128);
        gemm_bf16<<<grid, 256, 0, stream>>>(A1, lda1, K1, A2, lda2, WT, bias, rs,
                                            C, ldc, n, Ktot, act, outf32);
    };

    const int ggrid = (int)(((long long)n * 64 + 255) / 256);
    for (int l = 0; l < 4; ++l) {
        if (l == 0) {
            fused_pre<<<gx, 256, 0, stream>>>(x, pre_wt, pre_b, c_wt0, dinv,
                                              emb, 512, g, n);
        } else {
            int K = 128 * (l + 1);
            gemm(emb, 512, K, emb, 512, c_wt[l], nullptr, dinv, g, 128, K, 128, 0, 0);
        }
        bf16* out = (l < 3) ? (emb + (size_t)128 * (l + 1)) : h4;
        int ldo = (l < 3) ? 512 : 128;
        gcn_gather<<<ggrid, 256, 0, stream>>>(rp, csr, g, dinv, conv_b[l], out, ldo, n);
    }

    // post_mp: single fused kernel (pipelined stage 0 + T14 stages 1-3)
    fused_post<<<gx2, 256, 0, stream>>>(emb, 512, h4,
                                        p1_wt, post_b1, p2_wt, post_b2,
                                        p3_wt, post_b3, p4_wt, post_b4,
                                        (float*)d_out, n);
}